// Round 6
// baseline (795.548 us; speedup 1.0000x reference)
//
#include <hip/hip_runtime.h>
#include <math.h>

#define NNODES 100000
#define NEDGES 1600000
#define DD 64
#define EPS 1e-8f

#define NBUCK 512
#define BW 196            // bucket width: nodes per bucket (512*196 >= 100000)
#define BIN_BLOCKS 512
#define BIN_CHUNK ((NEDGES + BIN_BLOCKS - 1) / BIN_BLOCKS)   // 3125
#define BIN_CAP 28        // LDS staging entries per bucket (overflow -> direct)
#define CAP4 512

typedef unsigned short us8 __attribute__((ext_vector_type(8)));

__device__ __forceinline__ float wave_sum(float v) {
    #pragma unroll
    for (int off = 32; off; off >>= 1) v += __shfl_xor(v, off, 64);
    return v;
}

__device__ __forceinline__ float hinner(float u, float v, float sgn) {
    return wave_sum(sgn * u * v);
}

__device__ __forceinline__ float cross_ratio(float r0, float r1, float r2, float r3, float sgn) {
    float A = hinner(r0, r2, sgn);
    float B = hinner(r1, r3, sgn);
    float C = hinner(r0, r3, sgn);
    float Dv = hinner(r1, r2, sgn);
    return (A * B) / (C * Dv + EPS);
}

__device__ __forceinline__ float restore_scale(float cr_i, float cr_c) {
    float ratio = cr_i / (cr_c + EPS);
    bool cond = (!__builtin_isnan(cr_c)) && (!__builtin_isnan(cr_i)) &&
                (fabsf(cr_c) > EPS) && (fabsf(cr_i) > EPS) && (ratio > EPS);
    float s = 1.0f;
    if (cond) {
        s = sqrtf(fabsf(ratio));
        if (!__builtin_isfinite(s)) s = 1.0f;
    }
    return s;
}

__device__ __forceinline__ unsigned short f2bf(float f) {
    unsigned u = __float_as_uint(f);
    unsigned r = (u + 0x7fffu + ((u >> 16) & 1u)) >> 16;
    return (unsigned short)r;
}

__device__ __forceinline__ float bf2f(unsigned short b) {
    return __uint_as_float(((unsigned)b) << 16);
}

__device__ __forceinline__ float bcast(float v, int lane) {
    return __int_as_float(__builtin_amdgcn_readlane(__float_as_int(v), lane));
}

// layer0: h0 = normalize(x @ W0 + b0). One wave per row; x row broadcast via
// wave-uniform scalar loads; W0 column in VGPRs; 4-way split FMA chain.
__global__ __launch_bounds__(256, 5) void k_layer0(const float* __restrict__ x,
                                                   const float* __restrict__ W0,
                                                   const float* __restrict__ b0,
                                                   unsigned short* __restrict__ h0b) {
    int lane = threadIdx.x & 63;
    float w0[DD];
    #pragma unroll
    for (int k = 0; k < DD; k++) w0[k] = W0[k * DD + lane];
    float bv = b0[lane];
    int wid = (blockIdx.x * 256 + threadIdx.x) >> 6;
    int nw = (gridDim.x * 256) >> 6;
    for (int row = wid; row < NNODES; row += nw) {
        int row_u = __builtin_amdgcn_readfirstlane(row);
        const float* xr = x + (size_t)row_u * DD;
        float a0 = bv, a1 = 0.0f, a2 = 0.0f, a3 = 0.0f;
        #pragma unroll
        for (int k = 0; k < DD; k += 4) {
            a0 = fmaf(xr[k],     w0[k],     a0);
            a1 = fmaf(xr[k + 1], w0[k + 1], a1);
            a2 = fmaf(xr[k + 2], w0[k + 2], a2);
            a3 = fmaf(xr[k + 3], w0[k + 3], a3);
        }
        float acc = (a0 + a1) + (a2 + a3);
        float n = sqrtf(wave_sum(acc * acc));
        h0b[(size_t)row_u * DD + lane] = f2bf(acc / (n + EPS));
    }
}

// 512-bucket histogram of dst (LDS-staged)
__global__ __launch_bounds__(256) void k_hist512(const int* __restrict__ ei,
                                                 int* __restrict__ bhist) {
    __shared__ int h[NBUCK];
    for (int i = threadIdx.x; i < NBUCK; i += 256) h[i] = 0;
    __syncthreads();
    int tid = blockIdx.x * 256 + threadIdx.x;
    int stride = gridDim.x * 256;
    for (int e = tid; e < NEDGES; e += stride)
        atomicAdd(&h[(unsigned)ei[NEDGES + e] / BW], 1);
    __syncthreads();
    for (int i = threadIdx.x; i < NBUCK; i += 256)
        if (h[i]) atomicAdd(&bhist[i], h[i]);
}

// exclusive scan of 512 bucket counts -> bstart, gcur
__global__ __launch_bounds__(NBUCK) void k_scan512(const int* __restrict__ bhist,
                                                   int* __restrict__ bstart,
                                                   int* __restrict__ gcur) {
    __shared__ int s[NBUCK];
    int t = threadIdx.x;
    int v = bhist[t];
    s[t] = v;
    __syncthreads();
    for (int off = 1; off < NBUCK; off <<= 1) {
        int u = (t >= off) ? s[t - off] : 0;
        __syncthreads();
        s[t] += u;
        __syncthreads();
    }
    bstart[t] = s[t] - v;
    gcur[t] = s[t] - v;
}

// bin edges into per-bucket runs: pack = (src<<8)|dst_local, staged in LDS,
// flushed densely per bucket (one thread, consecutive addresses -> full lines).
__global__ __launch_bounds__(256) void k_bin(const int* __restrict__ ei,
                                             int* __restrict__ gcur,
                                             unsigned* __restrict__ colpack) {
    __shared__ unsigned stag[NBUCK * BIN_CAP];
    __shared__ int lcnt[NBUCK];
    int t = threadIdx.x;
    for (int i = t; i < NBUCK; i += 256) lcnt[i] = 0;
    __syncthreads();
    int lo = blockIdx.x * BIN_CHUNK;
    int hi = lo + BIN_CHUNK; if (hi > NEDGES) hi = NEDGES;
    for (int e = lo + t; e < hi; e += 256) {
        int d = ei[NEDGES + e];
        int s = ei[e];
        unsigned b = (unsigned)d / BW;
        unsigned dl = (unsigned)d - b * BW;
        unsigned pk = ((unsigned)s << 8) | dl;
        int slot = atomicAdd(&lcnt[b], 1);
        if (slot < BIN_CAP) {
            stag[b * BIN_CAP + slot] = pk;
        } else {
            colpack[atomicAdd(&gcur[b], 1)] = pk;   // rare overflow: direct
        }
    }
    __syncthreads();
    for (int b = t; b < NBUCK; b += 256) {
        int cnt = lcnt[b];
        if (cnt > BIN_CAP) cnt = BIN_CAP;
        if (cnt > 0) {
            int base = atomicAdd(&gcur[b], cnt);
            for (int i = 0; i < cnt; i++)
                colpack[base + i] = stag[b * BIN_CAP + i];
        }
    }
}

// collect neighbor (src) lists of rows 0..3 for the exact fp32 head path
__global__ __launch_bounds__(256) void k_find4(const int* __restrict__ ei,
                                               int* __restrict__ cnt4,
                                               int* __restrict__ list4) {
    int tid = blockIdx.x * 256 + threadIdx.x;
    int stride = gridDim.x * 256;
    for (int e = tid; e < NEDGES; e += stride) {
        int d = ei[NEDGES + e];
        if ((unsigned)d < 4u) {
            int p = atomicAdd(&cnt4[d], 1);
            if (p < CAP4) list4[d * CAP4 + p] = ei[e];
        }
    }
}

// one block per bucket: LDS-accumulate gathered bf16 rows (float LDS atomics),
// count degree, write fp32 mean coalesced. acc stride 65 breaks bank aliasing.
__global__ __launch_bounds__(256) void k_aggB(const unsigned short* __restrict__ h0b,
                                              const unsigned* __restrict__ colpack,
                                              const int* __restrict__ bstart,
                                              const int* __restrict__ bhist,
                                              float* __restrict__ agg) {
    __shared__ float acc[BW * 65];
    __shared__ int degL[BW];
    int t = threadIdx.x;
    for (int i = t; i < BW * 65; i += 256) acc[i] = 0.0f;
    for (int i = t; i < BW; i += 256) degL[i] = 0;
    __syncthreads();
    int b = blockIdx.x;
    int start = bstart[b], n = bhist[b];
    int lane = t & 63;
    int w = t >> 6;          // 4 waves
    int q = lane & 7;        // channel octet 8q..8q+7
    int g = lane >> 3;       // edge group 0..7
    for (int i = w * 8; i < n; i += 32) {
        int e = i + g;
        if (e < n) {
            unsigned pk = colpack[start + e];
            int src = pk >> 8;
            int dl = pk & 255;
            us8 u = *(const us8*)(h0b + (size_t)src * DD + q * 8);
            #pragma unroll
            for (int j = 0; j < 8; j++)
                atomicAdd(&acc[dl * 65 + q * 8 + j], bf2f(u[j]));
            if (q == 0) atomicAdd(&degL[dl], 1);
        }
    }
    __syncthreads();
    for (int dl = w; dl < BW; dl += 4) {
        int node = b * BW + dl;
        if (node < NNODES) {
            float inv = 1.0f / fmaxf((float)degL[dl], 1.0f);
            agg[(size_t)node * DD + lane] = acc[dl * 65 + lane] * inv;
        }
    }
}

// head kernel (4 waves): rows 0..3 through the full pipeline in fp32 -> s1, s2.
__global__ __launch_bounds__(256) void k_head(const float* __restrict__ x,
                       const float* __restrict__ W0, const float* __restrict__ b0,
                       const int* __restrict__ cnt4, const int* __restrict__ list4,
                       const float* __restrict__ Wm, const float* __restrict__ bm,
                       const float* __restrict__ W1, const float* __restrict__ b1,
                       float* __restrict__ scal) {
    __shared__ float hs[4][DD];
    __shared__ float h2s[4][DD];
    __shared__ float frs[4][DD];
    int lane = threadIdx.x & 63;
    int w = threadIdx.x >> 6;
    float sgn = (lane == 63) ? -1.0f : 1.0f;

    float w0[DD];
    #pragma unroll
    for (int k = 0; k < DD; k++) w0[k] = W0[k * DD + lane];
    float b0v = b0[lane];

    auto h0row = [&](int r) -> float {
        float xv = x[(size_t)r * DD + lane];
        float acc = b0v;
        #pragma unroll
        for (int k = 0; k < DD; k++)
            acc = fmaf(bcast(xv, k), w0[k], acc);
        float n = sqrtf(wave_sum(acc * acc));
        return acc / (n + EPS);
    };

    hs[w][lane] = h0row(w);

    int cnt = cnt4[w];
    if (cnt > CAP4) cnt = CAP4;
    float sum = 0.0f;
    for (int i = 0; i < cnt; i++) sum += h0row(list4[w * CAP4 + i]);
    float av = sum / fmaxf((float)cnt, 1.0f);
    float acc = bm[lane];
    #pragma unroll
    for (int k = 0; k < DD; k++)
        acc = fmaf(bcast(av, k), Wm[k * DD + lane], acc);
    float n = sqrtf(wave_sum(acc * acc));
    h2s[w][lane] = acc / (n + EPS);
    __syncthreads();

    float cr_init = cross_ratio(x[lane], x[DD + lane], x[2 * DD + lane], x[3 * DD + lane], sgn);
    float cr0 = cross_ratio(hs[0][lane], hs[1][lane], hs[2][lane], hs[3][lane], sgn);
    float cr_cur = cross_ratio(h2s[0][lane], h2s[1][lane], h2s[2][lane], h2s[3][lane], sgn);
    float s1 = restore_scale(cr0, cr_cur);

    float hv = h2s[w][lane] * s1;
    float acc2 = b1[lane];
    #pragma unroll
    for (int k = 0; k < DD; k++)
        acc2 = fmaf(bcast(hv, k), W1[k * DD + lane], acc2);
    n = sqrtf(wave_sum(acc2 * acc2));
    frs[w][lane] = fmaxf(acc2 / (n + EPS), 0.0f);
    __syncthreads();

    if (w == 0) {
        float cr2 = cross_ratio(frs[0][lane], frs[1][lane], frs[2][lane], frs[3][lane], sgn);
        float s2 = restore_scale(cr_init, cr2);
        if (lane == 0) { scal[0] = s1; scal[1] = s2; }
    }
}

// dense per-row: data(=agg, in place) -> Wm GEMV -> norm -> *s1 -> W1 GEMV
// -> norm -> relu -> *s2. Weights VGPR-resident; 4-way split FMA chains.
__global__ __launch_bounds__(256, 3) void k_mlp(float* data,
                                                const float* __restrict__ Wm,
                                                const float* __restrict__ bm,
                                                const float* __restrict__ W1,
                                                const float* __restrict__ b1,
                                                const float* __restrict__ scal) {
    int lane = threadIdx.x & 63;
    float wm[DD], w1[DD];
    #pragma unroll
    for (int k = 0; k < DD; k++) { wm[k] = Wm[k * DD + lane]; w1[k] = W1[k * DD + lane]; }
    float bmv = bm[lane], b1v = b1[lane];
    float s1 = scal[0], s2 = scal[1];
    int wid = (blockIdx.x * 256 + threadIdx.x) >> 6;
    int nw = (gridDim.x * 256) >> 6;
    for (int row = wid; row < NNODES; row += nw) {
        float av = data[(size_t)row * DD + lane];
        float a0 = bmv, a1 = 0.0f, a2 = 0.0f, a3 = 0.0f;
        #pragma unroll
        for (int k = 0; k < DD; k += 4) {
            a0 = fmaf(bcast(av, k),     wm[k],     a0);
            a1 = fmaf(bcast(av, k + 1), wm[k + 1], a1);
            a2 = fmaf(bcast(av, k + 2), wm[k + 2], a2);
            a3 = fmaf(bcast(av, k + 3), wm[k + 3], a3);
        }
        float acc = (a0 + a1) + (a2 + a3);
        float n = sqrtf(wave_sum(acc * acc));
        float h2 = (acc / (n + EPS)) * s1;
        float c0 = b1v, c1 = 0.0f, c2 = 0.0f, c3 = 0.0f;
        #pragma unroll
        for (int k = 0; k < DD; k += 4) {
            c0 = fmaf(bcast(h2, k),     w1[k],     c0);
            c1 = fmaf(bcast(h2, k + 1), w1[k + 1], c1);
            c2 = fmaf(bcast(h2, k + 2), w1[k + 2], c2);
            c3 = fmaf(bcast(h2, k + 3), w1[k + 3], c3);
        }
        float acc2 = (c0 + c1) + (c2 + c3);
        n = sqrtf(wave_sum(acc2 * acc2));
        data[(size_t)row * DD + lane] = fmaxf(acc2 / (n + EPS), 0.0f) * s2;
    }
}

extern "C" void kernel_launch(void* const* d_in, const int* in_sizes, int n_in,
                              void* d_out, int out_size, void* d_ws, size_t ws_size,
                              hipStream_t stream) {
    const float* x  = (const float*)d_in[0];
    const int*   ei = (const int*)d_in[1];
    const float* W0 = (const float*)d_in[2];
    const float* b0 = (const float*)d_in[3];
    const float* Wm = (const float*)d_in[4];
    const float* bm = (const float*)d_in[5];
    const float* W1 = (const float*)d_in[6];
    const float* b1 = (const float*)d_in[7];
    float* out = (float*)d_out;

    // ws layout (~19.2 MB)
    unsigned short* h0b = (unsigned short*)d_ws;            // N*64 bf16 = 12.8 MB
    unsigned* colpack = (unsigned*)(h0b + (size_t)NNODES * DD);  // E = 6.4 MB
    int* bhist  = (int*)(colpack + NEDGES);                 // 512
    int* cnt4   = bhist + NBUCK;                            // 4
    int* bstart = cnt4 + 4;                                 // 512
    int* gcur   = bstart + NBUCK;                           // 512
    int* list4  = gcur + NBUCK;                             // 4*512
    float* scal = (float*)(list4 + 4 * CAP4);               // 2

    hipMemsetAsync(bhist, 0, (NBUCK + 4) * sizeof(int), stream);  // bhist + cnt4

    k_layer0 <<<2048, 256, 0, stream>>>(x, W0, b0, h0b);
    k_hist512<<<512, 256, 0, stream>>>(ei, bhist);
    k_scan512<<<1, NBUCK, 0, stream>>>(bhist, bstart, gcur);
    k_bin    <<<BIN_BLOCKS, 256, 0, stream>>>(ei, gcur, colpack);
    k_find4  <<<512, 256, 0, stream>>>(ei, cnt4, list4);
    k_aggB   <<<NBUCK, 256, 0, stream>>>(h0b, colpack, bstart, bhist, out);
    k_head   <<<1, 256, 0, stream>>>(x, W0, b0, cnt4, list4, Wm, bm, W1, b1, scal);
    k_mlp    <<<2048, 256, 0, stream>>>(out, Wm, bm, W1, b1, scal);
}

// Round 7
// 364.755 us; speedup vs baseline: 2.1810x; 2.1810x over previous
//
#include <hip/hip_runtime.h>
#include <math.h>

#define NNODES 100000
#define NEDGES 1600000
#define DD 64
#define EPS 1e-8f
#define SCAN_B 1024
#define SCAN_NB ((NNODES + SCAN_B - 1) / SCAN_B)   // 98

#define NBUCK 1024
#define BW 98                 // nodes per bucket; 1024*98 >= 100000, BW < 256
#define BIN_BLOCKS 256
#define BIN_CHUNK ((NEDGES + BIN_BLOCKS - 1) / BIN_BLOCKS)  // 6250
#define BIN_CAP 16            // LDS staging per bucket per block (mean ~6.1)
#define SORT_CAP 4096         // max bucket size for in-register sort (mean ~1562)

typedef unsigned short us8 __attribute__((ext_vector_type(8)));

__device__ __forceinline__ float wave_sum(float v) {
    #pragma unroll
    for (int off = 32; off; off >>= 1) v += __shfl_xor(v, off, 64);
    return v;
}

__device__ __forceinline__ float hinner(float u, float v, float sgn) {
    return wave_sum(sgn * u * v);
}

__device__ __forceinline__ float cross_ratio(float r0, float r1, float r2, float r3, float sgn) {
    float A = hinner(r0, r2, sgn);
    float B = hinner(r1, r3, sgn);
    float C = hinner(r0, r3, sgn);
    float Dv = hinner(r1, r2, sgn);
    return (A * B) / (C * Dv + EPS);
}

__device__ __forceinline__ float restore_scale(float cr_i, float cr_c) {
    float ratio = cr_i / (cr_c + EPS);
    bool cond = (!__builtin_isnan(cr_c)) && (!__builtin_isnan(cr_i)) &&
                (fabsf(cr_c) > EPS) && (fabsf(cr_i) > EPS) && (ratio > EPS);
    float s = 1.0f;
    if (cond) {
        s = sqrtf(fabsf(ratio));
        if (!__builtin_isfinite(s)) s = 1.0f;
    }
    return s;
}

__device__ __forceinline__ unsigned short f2bf(float f) {
    unsigned u = __float_as_uint(f);
    unsigned r = (u + 0x7fffu + ((u >> 16) & 1u)) >> 16;
    return (unsigned short)r;
}

__device__ __forceinline__ float bf2f(unsigned short b) {
    return __uint_as_float(((unsigned)b) << 16);
}

__device__ __forceinline__ float bcast(float v, int lane) {
    return __int_as_float(__builtin_amdgcn_readlane(__float_as_int(v), lane));
}

// layer0: h0 = normalize(x @ W0 + b0). One wave per row; x row broadcast via
// wave-uniform scalar loads; W0 column in VGPRs; 4-way split FMA chain.
__global__ __launch_bounds__(256, 5) void k_layer0(const float* __restrict__ x,
                                                   const float* __restrict__ W0,
                                                   const float* __restrict__ b0,
                                                   unsigned short* __restrict__ h0b) {
    int lane = threadIdx.x & 63;
    float w0[DD];
    #pragma unroll
    for (int k = 0; k < DD; k++) w0[k] = W0[k * DD + lane];
    float bv = b0[lane];
    int wid = (blockIdx.x * 256 + threadIdx.x) >> 6;
    int nw = (gridDim.x * 256) >> 6;
    for (int row = wid; row < NNODES; row += nw) {
        int row_u = __builtin_amdgcn_readfirstlane(row);
        const float* xr = x + (size_t)row_u * DD;
        float a0 = bv, a1 = 0.0f, a2 = 0.0f, a3 = 0.0f;
        #pragma unroll
        for (int k = 0; k < DD; k += 4) {
            a0 = fmaf(xr[k],     w0[k],     a0);
            a1 = fmaf(xr[k + 1], w0[k + 1], a1);
            a2 = fmaf(xr[k + 2], w0[k + 2], a2);
            a3 = fmaf(xr[k + 3], w0[k + 3], a3);
        }
        float acc = (a0 + a1) + (a2 + a3);
        float n = sqrtf(wave_sum(acc * acc));
        h0b[(size_t)row_u * DD + lane] = f2bf(acc / (n + EPS));
    }
}

// per-node degree histogram
__global__ __launch_bounds__(256) void k_hist(const int* __restrict__ ei,
                                              int* __restrict__ deg) {
    int tid = blockIdx.x * 256 + threadIdx.x;
    int stride = gridDim.x * 256;
    for (int e = tid; e < NEDGES; e += stride)
        atomicAdd(&deg[ei[NEDGES + e]], 1);
}

// scan phase 1
__global__ __launch_bounds__(SCAN_B) void k_scan1(const int* __restrict__ deg,
                                                  int* __restrict__ row_ptr,
                                                  int* __restrict__ blksum) {
    __shared__ int part[SCAN_B];
    int t = threadIdx.x;
    int i = blockIdx.x * SCAN_B + t;
    int v = (i < NNODES) ? deg[i] : 0;
    part[t] = v;
    __syncthreads();
    for (int off = 1; off < SCAN_B; off <<= 1) {
        int u = (t >= off) ? part[t - off] : 0;
        __syncthreads();
        part[t] += u;
        __syncthreads();
    }
    if (i < NNODES) row_ptr[i] = part[t] - v;
    if (t == SCAN_B - 1) blksum[blockIdx.x] = part[t];
}

// scan phase 2 (also zeroes the sort-overflow scratch cursor)
__global__ __launch_bounds__(128) void k_scan2(const int* __restrict__ blksum,
                                               int* __restrict__ blkoff,
                                               int* __restrict__ scratch_cur) {
    __shared__ int s[128];
    int t = threadIdx.x;
    int v = (t < SCAN_NB) ? blksum[t] : 0;
    s[t] = v;
    __syncthreads();
    for (int off = 1; off < 128; off <<= 1) {
        int u = (t >= off) ? s[t - off] : 0;
        __syncthreads();
        s[t] += u;
        __syncthreads();
    }
    if (t < SCAN_NB) blkoff[t] = s[t] - v;
    if (t == 0) scratch_cur[0] = 0;
}

// scan phase 3: final row_ptr
__global__ __launch_bounds__(SCAN_B) void k_scan3(int* __restrict__ row_ptr,
                                                  const int* __restrict__ blkoff) {
    int t = threadIdx.x;
    int i = blockIdx.x * SCAN_B + t;
    if (i < NNODES)
        row_ptr[i] += blkoff[blockIdx.x];
    if (i == 0) row_ptr[NNODES] = NEDGES;
}

// init bucket write cursors to the bucket's CSR window start
__global__ __launch_bounds__(NBUCK) void k_initg(const int* __restrict__ row_ptr,
                                                 int* __restrict__ gcur) {
    int t = threadIdx.x;
    int node = t * BW; if (node > NNODES) node = NNODES;
    gcur[t] = row_ptr[node];
}

// bin edges into per-bucket dense runs inside their CSR windows.
// pack = (src<<8) | dst_local; staged in LDS, flushed as dense runs.
__global__ __launch_bounds__(256) void k_bin(const int* __restrict__ ei,
                                             int* __restrict__ gcur,
                                             unsigned* __restrict__ colpack) {
    __shared__ unsigned stag[NBUCK * BIN_CAP];
    __shared__ int lcnt[NBUCK];
    int t = threadIdx.x;
    for (int i = t; i < NBUCK; i += 256) lcnt[i] = 0;
    __syncthreads();
    int lo = blockIdx.x * BIN_CHUNK;
    int hi = lo + BIN_CHUNK; if (hi > NEDGES) hi = NEDGES;
    for (int e = lo + t; e < hi; e += 256) {
        int d = ei[NEDGES + e];
        int s = ei[e];
        unsigned b = (unsigned)d / BW;
        unsigned dl = (unsigned)d - b * BW;
        unsigned pk = ((unsigned)s << 8) | dl;
        int slot = atomicAdd(&lcnt[b], 1);
        if (slot < BIN_CAP) {
            stag[b * BIN_CAP + slot] = pk;
        } else {
            colpack[atomicAdd(&gcur[b], 1)] = pk;   // rare overflow: direct
        }
    }
    __syncthreads();
    for (int b = t; b < NBUCK; b += 256) {
        int cnt = lcnt[b];
        if (cnt > BIN_CAP) cnt = BIN_CAP;
        if (cnt > 0) {
            int base = atomicAdd(&gcur[b], cnt);
            for (int i = 0; i < cnt; i++)
                colpack[base + i] = stag[b * BIN_CAP + i];
        }
    }
}

// one block per bucket: in-place LDS counting sort of the bucket's run into
// per-node CSR order. All global reads complete before any writes (barrier);
// all traffic stays in the bucket's ~6 KB window. colpack becomes plain src.
__global__ __launch_bounds__(256) void k_sort(unsigned* __restrict__ colpack,
                                              const int* __restrict__ row_ptr,
                                              int* __restrict__ scratch,
                                              int* __restrict__ scratch_cur) {
    __shared__ int lcur[BW];
    int b = blockIdx.x;
    int t = threadIdx.x;
    int nlo = b * BW; if (nlo > NNODES) nlo = NNODES;
    int nhi = nlo + BW; if (nhi > NNODES) nhi = NNODES;
    int base = row_ptr[nlo];
    int n = row_ptr[nhi] - base;
    if (n == 0) return;
    for (int i = t; i < BW; i += 256) {
        int node = nlo + i;
        lcur[i] = (node < nhi) ? (row_ptr[node] - base) : n;
    }
    __syncthreads();
    if (n <= SORT_CAP) {
        unsigned ent[SORT_CAP / 256];
        int cnt = 0;
        for (int i = t; i < n; i += 256) ent[cnt++] = colpack[base + i];
        int pos[SORT_CAP / 256];
        for (int j = 0; j < cnt; j++)
            pos[j] = atomicAdd(&lcur[ent[j] & 255u], 1);
        __syncthreads();   // all reads drained before any writes
        for (int j = 0; j < cnt; j++)
            colpack[base + pos[j]] = ent[j] >> 8;
    } else {
        // overflow fallback (never hit for this input): stage via global scratch
        int sb = 0;
        if (t == 0) sb = atomicAdd(scratch_cur, n);
        sb = __shfl(sb, 0, 64);
        sb = __builtin_amdgcn_readfirstlane(sb);
        for (int i = t; i < n; i += 256) scratch[sb + i] = (int)colpack[base + i];
        __syncthreads();
        for (int i = t; i < n; i += 256) {
            unsigned pk = (unsigned)scratch[sb + i];
            int p = atomicAdd(&lcur[pk & 255u], 1);
            colpack[base + p] = pk >> 8;
        }
    }
}

// pure gather-mean over CSR: one wave per dst row, 8 edges in flight
// (8 lanes x 16 B ushort8 each). Tiny VGPR footprint -> max occupancy.
__global__ __launch_bounds__(256) void k_agg(const unsigned short* __restrict__ h0b,
                                             const int* __restrict__ row_ptr,
                                             const int* __restrict__ col,
                                             float* __restrict__ agg) {
    int lane = threadIdx.x & 63;
    int q = lane & 7;    // channel octet: channels 8q..8q+7
    int g = lane >> 3;   // edge group 0..7
    int wid = (blockIdx.x * 256 + threadIdx.x) >> 6;
    int nw = (gridDim.x * 256) >> 6;
    for (int row = wid; row < NNODES; row += nw) {
        int start = row_ptr[row], end = row_ptr[row + 1];
        float s[8] = {0, 0, 0, 0, 0, 0, 0, 0};
        for (int cb = start; cb < end; cb += 64) {
            int c = (cb + lane < end) ? col[cb + lane] : 0;
            int m = end - cb; if (m > 64) m = 64;
            for (int j = 0; j < m; j += 8) {
                int e = j + g;
                bool val = e < m;
                int esafe = val ? e : 0;
                int src = __shfl(c, esafe, 64);      // full wave active
                us8 u = *(const us8*)(h0b + (size_t)src * DD + q * 8);
                float f = val ? 1.0f : 0.0f;
                #pragma unroll
                for (int i = 0; i < 8; i++)
                    s[i] = fmaf(f, bf2f(u[i]), s[i]);
            }
        }
        #pragma unroll
        for (int i = 0; i < 8; i++) {
            s[i] += __shfl_xor(s[i], 8, 64);
            s[i] += __shfl_xor(s[i], 16, 64);
            s[i] += __shfl_xor(s[i], 32, 64);
        }
        if (g == 0) {
            float inv = 1.0f / fmaxf((float)(end - start), 1.0f);
            float4* dst = (float4*)(agg + (size_t)row * DD + q * 8);
            float4 o0 = {s[0] * inv, s[1] * inv, s[2] * inv, s[3] * inv};
            float4 o1 = {s[4] * inv, s[5] * inv, s[6] * inv, s[7] * inv};
            dst[0] = o0;
            dst[1] = o1;
        }
    }
}

// head kernel (4 waves): rows 0..3 through the full pipeline in fp32 -> s1, s2.
__global__ __launch_bounds__(256) void k_head(const float* __restrict__ x,
                       const float* __restrict__ W0, const float* __restrict__ b0,
                       const int* __restrict__ row_ptr, const int* __restrict__ col,
                       const float* __restrict__ Wm, const float* __restrict__ bm,
                       const float* __restrict__ W1, const float* __restrict__ b1,
                       float* __restrict__ scal) {
    __shared__ float hs[4][DD];
    __shared__ float h2s[4][DD];
    __shared__ float frs[4][DD];
    int lane = threadIdx.x & 63;
    int w = threadIdx.x >> 6;
    float sgn = (lane == 63) ? -1.0f : 1.0f;

    float w0[DD];
    #pragma unroll
    for (int k = 0; k < DD; k++) w0[k] = W0[k * DD + lane];
    float b0v = b0[lane];

    auto h0row = [&](int r) -> float {
        float xv = x[(size_t)r * DD + lane];
        float acc = b0v;
        #pragma unroll
        for (int k = 0; k < DD; k++)
            acc = fmaf(bcast(xv, k), w0[k], acc);
        float n = sqrtf(wave_sum(acc * acc));
        return acc / (n + EPS);
    };

    hs[w][lane] = h0row(w);

    int start = row_ptr[w], end = row_ptr[w + 1];
    float sum = 0.0f;
    for (int i = start; i < end; i++) sum += h0row(col[i]);
    float av = sum / fmaxf((float)(end - start), 1.0f);
    float acc = bm[lane];
    #pragma unroll
    for (int k = 0; k < DD; k++)
        acc = fmaf(bcast(av, k), Wm[k * DD + lane], acc);
    float n = sqrtf(wave_sum(acc * acc));
    h2s[w][lane] = acc / (n + EPS);
    __syncthreads();

    float cr_init = cross_ratio(x[lane], x[DD + lane], x[2 * DD + lane], x[3 * DD + lane], sgn);
    float cr0 = cross_ratio(hs[0][lane], hs[1][lane], hs[2][lane], hs[3][lane], sgn);
    float cr_cur = cross_ratio(h2s[0][lane], h2s[1][lane], h2s[2][lane], h2s[3][lane], sgn);
    float s1 = restore_scale(cr0, cr_cur);

    float hv = h2s[w][lane] * s1;
    float acc2 = b1[lane];
    #pragma unroll
    for (int k = 0; k < DD; k++)
        acc2 = fmaf(bcast(hv, k), W1[k * DD + lane], acc2);
    n = sqrtf(wave_sum(acc2 * acc2));
    frs[w][lane] = fmaxf(acc2 / (n + EPS), 0.0f);
    __syncthreads();

    if (w == 0) {
        float cr2 = cross_ratio(frs[0][lane], frs[1][lane], frs[2][lane], frs[3][lane], sgn);
        float s2 = restore_scale(cr_init, cr2);
        if (lane == 0) { scal[0] = s1; scal[1] = s2; }
    }
}

// dense per-row MLP, agg in place in d_out. Weights VGPR-resident.
__global__ __launch_bounds__(256, 3) void k_mlp(float* data,
                                                const float* __restrict__ Wm,
                                                const float* __restrict__ bm,
                                                const float* __restrict__ W1,
                                                const float* __restrict__ b1,
                                                const float* __restrict__ scal) {
    int lane = threadIdx.x & 63;
    float wm[DD], w1[DD];
    #pragma unroll
    for (int k = 0; k < DD; k++) { wm[k] = Wm[k * DD + lane]; w1[k] = W1[k * DD + lane]; }
    float bmv = bm[lane], b1v = b1[lane];
    float s1 = scal[0], s2 = scal[1];
    int wid = (blockIdx.x * 256 + threadIdx.x) >> 6;
    int nw = (gridDim.x * 256) >> 6;
    for (int row = wid; row < NNODES; row += nw) {
        float av = data[(size_t)row * DD + lane];
        float a0 = bmv, a1 = 0.0f, a2 = 0.0f, a3 = 0.0f;
        #pragma unroll
        for (int k = 0; k < DD; k += 4) {
            a0 = fmaf(bcast(av, k),     wm[k],     a0);
            a1 = fmaf(bcast(av, k + 1), wm[k + 1], a1);
            a2 = fmaf(bcast(av, k + 2), wm[k + 2], a2);
            a3 = fmaf(bcast(av, k + 3), wm[k + 3], a3);
        }
        float acc = (a0 + a1) + (a2 + a3);
        float n = sqrtf(wave_sum(acc * acc));
        float h2 = (acc / (n + EPS)) * s1;
        float c0 = b1v, c1 = 0.0f, c2 = 0.0f, c3 = 0.0f;
        #pragma unroll
        for (int k = 0; k < DD; k += 4) {
            c0 = fmaf(bcast(h2, k),     w1[k],     c0);
            c1 = fmaf(bcast(h2, k + 1), w1[k + 1], c1);
            c2 = fmaf(bcast(h2, k + 2), w1[k + 2], c2);
            c3 = fmaf(bcast(h2, k + 3), w1[k + 3], c3);
        }
        float acc2 = (c0 + c1) + (c2 + c3);
        n = sqrtf(wave_sum(acc2 * acc2));
        data[(size_t)row * DD + lane] = fmaxf(acc2 / (n + EPS), 0.0f) * s2;
    }
}

extern "C" void kernel_launch(void* const* d_in, const int* in_sizes, int n_in,
                              void* d_out, int out_size, void* d_ws, size_t ws_size,
                              hipStream_t stream) {
    const float* x  = (const float*)d_in[0];
    const int*   ei = (const int*)d_in[1];
    const float* W0 = (const float*)d_in[2];
    const float* b0 = (const float*)d_in[3];
    const float* Wm = (const float*)d_in[4];
    const float* bm = (const float*)d_in[5];
    const float* W1 = (const float*)d_in[6];
    const float* b1 = (const float*)d_in[7];
    float* out = (float*)d_out;

    // ws layout (~20.0 MB)
    unsigned short* h0b = (unsigned short*)d_ws;                 // N*64 bf16 = 12.8 MB
    int* deg     = (int*)(h0b + (size_t)NNODES * DD);            // N (reused as sort scratch)
    int* row_ptr = deg + NNODES;                                 // N+1
    unsigned* colpack = (unsigned*)(row_ptr + NNODES + 1);       // E = 6.4 MB
    int* gcur    = (int*)(colpack + NEDGES);                     // NBUCK
    int* blksum  = gcur + NBUCK;                                 // 128
    int* blkoff  = blksum + 128;                                 // 128
    int* scur    = blkoff + 128;                                 // 1
    float* scal  = (float*)(scur + 1);                           // 2

    hipMemsetAsync(deg, 0, NNODES * sizeof(int), stream);

    k_layer0<<<2048, 256, 0, stream>>>(x, W0, b0, h0b);
    k_hist  <<<1024, 256, 0, stream>>>(ei, deg);
    k_scan1 <<<SCAN_NB, SCAN_B, 0, stream>>>(deg, row_ptr, blksum);
    k_scan2 <<<1, 128, 0, stream>>>(blksum, blkoff, scur);
    k_scan3 <<<SCAN_NB, SCAN_B, 0, stream>>>(row_ptr, blkoff);
    k_initg <<<1, NBUCK, 0, stream>>>(row_ptr, gcur);
    k_bin   <<<BIN_BLOCKS, 256, 0, stream>>>(ei, gcur, colpack);
    k_sort  <<<NBUCK, 256, 0, stream>>>(colpack, row_ptr, deg, scur);
    k_agg   <<<4096, 256, 0, stream>>>(h0b, row_ptr, (const int*)colpack, out);
    k_head  <<<1, 256, 0, stream>>>(x, W0, b0, row_ptr, (const int*)colpack, Wm, bm, W1, b1, scal);
    k_mlp   <<<2048, 256, 0, stream>>>(out, Wm, bm, W1, b1, scal);
}

// Round 9
// 300.006 us; speedup vs baseline: 2.6518x; 1.2158x over previous
//
#include <hip/hip_runtime.h>
#include <math.h>

#define NNODES 100000
#define NEDGES 1600000
#define DD 64
#define EPS 1e-8f
#define SCAN_B 1024
#define SCAN_NB ((NNODES + SCAN_B - 1) / SCAN_B)   // 98

#define NBUCK 1024
#define BW 98
#define BIN_BLOCKS 256
#define BIN_CHUNK ((NEDGES + BIN_BLOCKS - 1) / BIN_BLOCKS)  // 6250
#define BIN_CAP 16
#define SORT_CAP 4096
#define NTILES (NNODES / 16)   // 6250, exact

typedef unsigned short us8 __attribute__((ext_vector_type(8)));
typedef short short8 __attribute__((ext_vector_type(8)));
typedef float f32x4 __attribute__((ext_vector_type(4)));

__device__ __forceinline__ float wave_sum(float v) {
    #pragma unroll
    for (int off = 32; off; off >>= 1) v += __shfl_xor(v, off, 64);
    return v;
}

__device__ __forceinline__ float hinner(float u, float v, float sgn) {
    return wave_sum(sgn * u * v);
}

__device__ __forceinline__ float cross_ratio(float r0, float r1, float r2, float r3, float sgn) {
    float A = hinner(r0, r2, sgn);
    float B = hinner(r1, r3, sgn);
    float C = hinner(r0, r3, sgn);
    float Dv = hinner(r1, r2, sgn);
    return (A * B) / (C * Dv + EPS);
}

__device__ __forceinline__ float restore_scale(float cr_i, float cr_c) {
    float ratio = cr_i / (cr_c + EPS);
    bool cond = (!__builtin_isnan(cr_c)) && (!__builtin_isnan(cr_i)) &&
                (fabsf(cr_c) > EPS) && (fabsf(cr_i) > EPS) && (ratio > EPS);
    float s = 1.0f;
    if (cond) {
        s = sqrtf(fabsf(ratio));
        if (!__builtin_isfinite(s)) s = 1.0f;
    }
    return s;
}

__device__ __forceinline__ unsigned short f2bf(float f) {
    unsigned u = __float_as_uint(f);
    unsigned r = (u + 0x7fffu + ((u >> 16) & 1u)) >> 16;
    return (unsigned short)r;
}

__device__ __forceinline__ float bf2f(unsigned short b) {
    return __uint_as_float(((unsigned)b) << 16);
}

__device__ __forceinline__ float bcast(float v, int lane) {
    return __int_as_float(__builtin_amdgcn_readlane(__float_as_int(v), lane));
}

// load one weight matrix as split-bf16 B fragments: frag (t,h) lane l holds
// W[h*32 + (l>>4)*8 + j][t*16 + (l&15)], j=0..7
__device__ __forceinline__ void load_bfrags(const float* __restrict__ W, int lane,
                                            short8 bhi[4][2], short8 blo[4][2]) {
    int c = lane & 15, q = lane >> 4;
    #pragma unroll
    for (int t = 0; t < 4; t++)
        #pragma unroll
        for (int h = 0; h < 2; h++) {
            short8 hi8, lo8;
            #pragma unroll
            for (int j = 0; j < 8; j++) {
                float w = W[(h * 32 + q * 8 + j) * DD + t * 16 + c];
                unsigned short hb = f2bf(w);
                float r = w - bf2f(hb);
                hi8[j] = (short)hb;
                lo8[j] = (short)f2bf(r);
            }
            bhi[t][h] = hi8;
            blo[t][h] = lo8;
        }
}

// build split-bf16 A fragment from 8 consecutive floats
__device__ __forceinline__ void build_a(const float* p, short8& hi, short8& lo) {
    float4 f0 = *(const float4*)p;
    float4 f1 = *(const float4*)(p + 4);
    float av[8] = {f0.x, f0.y, f0.z, f0.w, f1.x, f1.y, f1.z, f1.w};
    short8 h8, l8;
    #pragma unroll
    for (int j = 0; j < 8; j++) {
        unsigned short hb = f2bf(av[j]);
        float r = av[j] - bf2f(hb);
        h8[j] = (short)hb;
        l8[j] = (short)f2bf(r);
    }
    hi = h8;
    lo = l8;
}

#define MFMA3(cacc, ahi, alo, t, h)                                              \
    cacc = __builtin_amdgcn_mfma_f32_16x16x32_bf16(ahi, bhi[t][h], cacc, 0, 0, 0); \
    cacc = __builtin_amdgcn_mfma_f32_16x16x32_bf16(alo, bhi[t][h], cacc, 0, 0, 0); \
    cacc = __builtin_amdgcn_mfma_f32_16x16x32_bf16(ahi, blo[t][h], cacc, 0, 0, 0);

// layer0 via MFMA: h0b = bf16(normalize(x @ W0 + b0)), 16 rows per wave-tile.
__global__ __launch_bounds__(256, 3) void k_layer0M(const float* __restrict__ x,
                                                    const float* __restrict__ W0,
                                                    const float* __restrict__ b0,
                                                    unsigned short* __restrict__ h0b) {
    int lane = threadIdx.x & 63;
    int c = lane & 15, q = lane >> 4;
    short8 bhi[4][2], blo[4][2];
    load_bfrags(W0, lane, bhi, blo);
    float badd[4];
    #pragma unroll
    for (int t = 0; t < 4; t++) badd[t] = b0[t * 16 + c];
    int wid = (blockIdx.x * 256 + threadIdx.x) >> 6;
    int nw = (gridDim.x * 256) >> 6;
    for (int tile = wid; tile < NTILES; tile += nw) {
        int R = tile * 16;
        f32x4 cc[4] = {{0, 0, 0, 0}, {0, 0, 0, 0}, {0, 0, 0, 0}, {0, 0, 0, 0}};
        #pragma unroll
        for (int h = 0; h < 2; h++) {
            short8 ahi, alo;
            build_a(x + ((size_t)(R + c) << 6) + h * 32 + q * 8, ahi, alo);
            #pragma unroll
            for (int t = 0; t < 4; t++) { MFMA3(cc[t], ahi, alo, t, h); }
        }
        float ss[4];
        #pragma unroll
        for (int r = 0; r < 4; r++) {
            #pragma unroll
            for (int t = 0; t < 4; t++) cc[t][r] += badd[t];
            ss[r] = cc[0][r] * cc[0][r] + cc[1][r] * cc[1][r] +
                    cc[2][r] * cc[2][r] + cc[3][r] * cc[3][r];
        }
        #pragma unroll
        for (int off = 1; off <= 8; off <<= 1) {
            #pragma unroll
            for (int r = 0; r < 4; r++) ss[r] += __shfl_xor(ss[r], off, 64);
        }
        #pragma unroll
        for (int r = 0; r < 4; r++) {
            float sc = 1.0f / (sqrtf(ss[r]) + EPS);
            int row = R + q * 4 + r;
            #pragma unroll
            for (int t = 0; t < 4; t++)
                h0b[(size_t)row * DD + t * 16 + c] = f2bf(cc[t][r] * sc);
        }
    }
}

// fused GEMM + normalize epilogue, in place on `data`.
// mode 1: out = normalize(data@W + b) * scal[0]
// mode 2: out = relu(normalize(data@W + b)) * scal[1]
__global__ __launch_bounds__(256, 3) void k_gemm(float* data,
                                                 const float* __restrict__ W,
                                                 const float* __restrict__ bias,
                                                 const float* __restrict__ scal,
                                                 int mode) {
    int lane = threadIdx.x & 63;
    int c = lane & 15, q = lane >> 4;
    short8 bhi[4][2], blo[4][2];
    load_bfrags(W, lane, bhi, blo);
    float badd[4];
    #pragma unroll
    for (int t = 0; t < 4; t++) badd[t] = bias[t * 16 + c];
    float s = (mode == 1) ? scal[0] : scal[1];
    int wid = (blockIdx.x * 256 + threadIdx.x) >> 6;
    int nw = (gridDim.x * 256) >> 6;
    for (int tile = wid; tile < NTILES; tile += nw) {
        int R = tile * 16;
        f32x4 cc[4] = {{0, 0, 0, 0}, {0, 0, 0, 0}, {0, 0, 0, 0}, {0, 0, 0, 0}};
        #pragma unroll
        for (int h = 0; h < 2; h++) {
            short8 ahi, alo;
            build_a(data + ((size_t)(R + c) << 6) + h * 32 + q * 8, ahi, alo);
            #pragma unroll
            for (int t = 0; t < 4; t++) { MFMA3(cc[t], ahi, alo, t, h); }
        }
        float ss[4];
        #pragma unroll
        for (int r = 0; r < 4; r++) {
            #pragma unroll
            for (int t = 0; t < 4; t++) cc[t][r] += badd[t];
            ss[r] = cc[0][r] * cc[0][r] + cc[1][r] * cc[1][r] +
                    cc[2][r] * cc[2][r] + cc[3][r] * cc[3][r];
        }
        #pragma unroll
        for (int off = 1; off <= 8; off <<= 1) {
            #pragma unroll
            for (int r = 0; r < 4; r++) ss[r] += __shfl_xor(ss[r], off, 64);
        }
        #pragma unroll
        for (int r = 0; r < 4; r++) {
            float sc = 1.0f / (sqrtf(ss[r]) + EPS);
            int row = R + q * 4 + r;
            #pragma unroll
            for (int t = 0; t < 4; t++) {
                float v = cc[t][r] * sc;
                if (mode == 2) v = fmaxf(v, 0.0f);
                data[(size_t)row * DD + t * 16 + c] = v * s;
            }
        }
    }
}

// per-node degree histogram
__global__ __launch_bounds__(256) void k_hist(const int* __restrict__ ei,
                                              int* __restrict__ deg) {
    int tid = blockIdx.x * 256 + threadIdx.x;
    int stride = gridDim.x * 256;
    for (int e = tid; e < NEDGES; e += stride)
        atomicAdd(&deg[ei[NEDGES + e]], 1);
}

__global__ __launch_bounds__(SCAN_B) void k_scan1(const int* __restrict__ deg,
                                                  int* __restrict__ row_ptr,
                                                  int* __restrict__ blksum) {
    __shared__ int part[SCAN_B];
    int t = threadIdx.x;
    int i = blockIdx.x * SCAN_B + t;
    int v = (i < NNODES) ? deg[i] : 0;
    part[t] = v;
    __syncthreads();
    for (int off = 1; off < SCAN_B; off <<= 1) {
        int u = (t >= off) ? part[t - off] : 0;
        __syncthreads();
        part[t] += u;
        __syncthreads();
    }
    if (i < NNODES) row_ptr[i] = part[t] - v;
    if (t == SCAN_B - 1) blksum[blockIdx.x] = part[t];
}

__global__ __launch_bounds__(128) void k_scan2(const int* __restrict__ blksum,
                                               int* __restrict__ blkoff,
                                               int* __restrict__ scratch_cur) {
    __shared__ int s[128];
    int t = threadIdx.x;
    int v = (t < SCAN_NB) ? blksum[t] : 0;
    s[t] = v;
    __syncthreads();
    for (int off = 1; off < 128; off <<= 1) {
        int u = (t >= off) ? s[t - off] : 0;
        __syncthreads();
        s[t] += u;
        __syncthreads();
    }
    if (t < SCAN_NB) blkoff[t] = s[t] - v;
    if (t == 0) scratch_cur[0] = 0;
}

// scan phase 3: final row_ptr + bucket cursor init (folded k_initg)
__global__ __launch_bounds__(SCAN_B) void k_scan3(int* __restrict__ row_ptr,
                                                  const int* __restrict__ blkoff,
                                                  int* __restrict__ gcur) {
    int t = threadIdx.x;
    int i = blockIdx.x * SCAN_B + t;
    if (i < NNODES) {
        int v = row_ptr[i] + blkoff[blockIdx.x];
        row_ptr[i] = v;
        if (i % BW == 0) gcur[i / BW] = v;
    }
    if (i == 0) {
        row_ptr[NNODES] = NEDGES;
        gcur[1021] = NEDGES;
        gcur[1022] = NEDGES;
        gcur[1023] = NEDGES;
    }
}

// bin edges into per-bucket dense runs inside their CSR windows.
__global__ __launch_bounds__(256) void k_bin(const int* __restrict__ ei,
                                             int* __restrict__ gcur,
                                             unsigned* __restrict__ colpack) {
    __shared__ unsigned stag[NBUCK * BIN_CAP];
    __shared__ int lcnt[NBUCK];
    int t = threadIdx.x;
    for (int i = t; i < NBUCK; i += 256) lcnt[i] = 0;
    __syncthreads();
    int lo = blockIdx.x * BIN_CHUNK;
    int hi = lo + BIN_CHUNK; if (hi > NEDGES) hi = NEDGES;
    for (int e = lo + t; e < hi; e += 256) {
        int d = ei[NEDGES + e];
        int s = ei[e];
        unsigned b = (unsigned)d / BW;
        unsigned dl = (unsigned)d - b * BW;
        unsigned pk = ((unsigned)s << 8) | dl;
        int slot = atomicAdd(&lcnt[b], 1);
        if (slot < BIN_CAP) {
            stag[b * BIN_CAP + slot] = pk;
        } else {
            colpack[atomicAdd(&gcur[b], 1)] = pk;
        }
    }
    __syncthreads();
    for (int b = t; b < NBUCK; b += 256) {
        int cnt = lcnt[b];
        if (cnt > BIN_CAP) cnt = BIN_CAP;
        if (cnt > 0) {
            int base = atomicAdd(&gcur[b], cnt);
            for (int i = 0; i < cnt; i++)
                colpack[base + i] = stag[b * BIN_CAP + i];
        }
    }
}

// one block per bucket: LDS counting sort of bucket run into CSR order.
__global__ __launch_bounds__(256) void k_sort(unsigned* __restrict__ colpack,
                                              const int* __restrict__ row_ptr,
                                              int* __restrict__ scratch,
                                              int* __restrict__ scratch_cur) {
    __shared__ int lcur[BW];
    int b = blockIdx.x;
    int t = threadIdx.x;
    int nlo = b * BW; if (nlo > NNODES) nlo = NNODES;
    int nhi = nlo + BW; if (nhi > NNODES) nhi = NNODES;
    int base = row_ptr[nlo];
    int n = row_ptr[nhi] - base;
    if (n == 0) return;
    for (int i = t; i < BW; i += 256) {
        int node = nlo + i;
        lcur[i] = (node < nhi) ? (row_ptr[node] - base) : n;
    }
    __syncthreads();
    if (n <= SORT_CAP) {
        unsigned ent[SORT_CAP / 256];
        int cnt = 0;
        for (int i = t; i < n; i += 256) ent[cnt++] = colpack[base + i];
        int pos[SORT_CAP / 256];
        for (int j = 0; j < cnt; j++)
            pos[j] = atomicAdd(&lcur[ent[j] & 255u], 1);
        __syncthreads();
        for (int j = 0; j < cnt; j++)
            colpack[base + pos[j]] = ent[j] >> 8;
    } else {
        int sb = 0;
        if (t == 0) sb = atomicAdd(scratch_cur, n);
        sb = __shfl(sb, 0, 64);
        sb = __builtin_amdgcn_readfirstlane(sb);
        for (int i = t; i < n; i += 256) scratch[sb + i] = (int)colpack[base + i];
        __syncthreads();
        for (int i = t; i < n; i += 256) {
            unsigned pk = (unsigned)scratch[sb + i];
            int p = atomicAdd(&lcur[pk & 255u], 1);
            colpack[base + p] = pk >> 8;
        }
    }
}

// pure gather-mean over CSR: one wave per dst row, 8 edges in flight.
__global__ __launch_bounds__(256) void k_agg(const unsigned short* __restrict__ h0b,
                                             const int* __restrict__ row_ptr,
                                             const int* __restrict__ col,
                                             float* __restrict__ agg) {
    int lane = threadIdx.x & 63;
    int q = lane & 7;
    int g = lane >> 3;
    int wid = (blockIdx.x * 256 + threadIdx.x) >> 6;
    int nw = (gridDim.x * 256) >> 6;
    for (int row = wid; row < NNODES; row += nw) {
        int start = row_ptr[row], end = row_ptr[row + 1];
        float s[8] = {0, 0, 0, 0, 0, 0, 0, 0};
        for (int cb = start; cb < end; cb += 64) {
            int c = (cb + lane < end) ? col[cb + lane] : 0;
            int m = end - cb; if (m > 64) m = 64;
            for (int j = 0; j < m; j += 8) {
                int e = j + g;
                bool val = e < m;
                int esafe = val ? e : 0;
                int src = __shfl(c, esafe, 64);
                us8 u = *(const us8*)(h0b + (size_t)src * DD + q * 8);
                float f = val ? 1.0f : 0.0f;
                #pragma unroll
                for (int i = 0; i < 8; i++)
                    s[i] = fmaf(f, bf2f(u[i]), s[i]);
            }
        }
        #pragma unroll
        for (int i = 0; i < 8; i++) {
            s[i] += __shfl_xor(s[i], 8, 64);
            s[i] += __shfl_xor(s[i], 16, 64);
            s[i] += __shfl_xor(s[i], 32, 64);
        }
        if (g == 0) {
            float inv = 1.0f / fmaxf((float)(end - start), 1.0f);
            float4* dst = (float4*)(agg + (size_t)row * DD + q * 8);
            float4 o0 = {s[0] * inv, s[1] * inv, s[2] * inv, s[3] * inv};
            float4 o1 = {s[4] * inv, s[5] * inv, s[6] * inv, s[7] * inv};
            dst[0] = o0;
            dst[1] = o1;
        }
    }
}

// head kernel (4 waves): rows 0..3 through the full pipeline in fp32 -> s1, s2.
__global__ __launch_bounds__(256) void k_head(const float* __restrict__ x,
                       const float* __restrict__ W0, const float* __restrict__ b0,
                       const int* __restrict__ row_ptr, const int* __restrict__ col,
                       const float* __restrict__ Wm, const float* __restrict__ bm,
                       const float* __restrict__ W1, const float* __restrict__ b1,
                       float* __restrict__ scal) {
    __shared__ float hs[4][DD];
    __shared__ float h2s[4][DD];
    __shared__ float frs[4][DD];
    int lane = threadIdx.x & 63;
    int w = threadIdx.x >> 6;
    float sgn = (lane == 63) ? -1.0f : 1.0f;

    float w0[DD];
    #pragma unroll
    for (int k = 0; k < DD; k++) w0[k] = W0[k * DD + lane];
    float b0v = b0[lane];

    auto h0row = [&](int r) -> float {
        float xv = x[(size_t)r * DD + lane];
        float acc = b0v;
        #pragma unroll
        for (int k = 0; k < DD; k++)
            acc = fmaf(bcast(xv, k), w0[k], acc);
        float n = sqrtf(wave_sum(acc * acc));
        return acc / (n + EPS);
    };

    hs[w][lane] = h0row(w);

    int start = row_ptr[w], end = row_ptr[w + 1];
    float sum = 0.0f;
    for (int i = start; i < end; i++) sum += h0row(col[i]);
    float av = sum / fmaxf((float)(end - start), 1.0f);
    float acc = bm[lane];
    #pragma unroll
    for (int k = 0; k < DD; k++)
        acc = fmaf(bcast(av, k), Wm[k * DD + lane], acc);
    float n = sqrtf(wave_sum(acc * acc));
    h2s[w][lane] = acc / (n + EPS);
    __syncthreads();

    float cr_init = cross_ratio(x[lane], x[DD + lane], x[2 * DD + lane], x[3 * DD + lane], sgn);
    float cr0 = cross_ratio(hs[0][lane], hs[1][lane], hs[2][lane], hs[3][lane], sgn);
    float cr_cur = cross_ratio(h2s[0][lane], h2s[1][lane], h2s[2][lane], h2s[3][lane], sgn);
    float s1 = restore_scale(cr0, cr_cur);

    float hv = h2s[w][lane] * s1;
    float acc2 = b1[lane];
    #pragma unroll
    for (int k = 0; k < DD; k++)
        acc2 = fmaf(bcast(hv, k), W1[k * DD + lane], acc2);
    n = sqrtf(wave_sum(acc2 * acc2));
    frs[w][lane] = fmaxf(acc2 / (n + EPS), 0.0f);
    __syncthreads();

    if (w == 0) {
        float cr2 = cross_ratio(frs[0][lane], frs[1][lane], frs[2][lane], frs[3][lane], sgn);
        float s2 = restore_scale(cr_init, cr2);
        if (lane == 0) { scal[0] = s1; scal[1] = s2; }
    }
}

extern "C" void kernel_launch(void* const* d_in, const int* in_sizes, int n_in,
                              void* d_out, int out_size, void* d_ws, size_t ws_size,
                              hipStream_t stream) {
    const float* x  = (const float*)d_in[0];
    const int*   ei = (const int*)d_in[1];
    const float* W0 = (const float*)d_in[2];
    const float* b0 = (const float*)d_in[3];
    const float* Wm = (const float*)d_in[4];
    const float* bm = (const float*)d_in[5];
    const float* W1 = (const float*)d_in[6];
    const float* b1 = (const float*)d_in[7];
    float* out = (float*)d_out;

    // ws layout (~20.0 MB)
    unsigned short* h0b = (unsigned short*)d_ws;                 // N*64 bf16 = 12.8 MB
    int* deg     = (int*)(h0b + (size_t)NNODES * DD);            // N (reused as sort scratch)
    int* row_ptr = deg + NNODES;                                 // N+1
    unsigned* colpack = (unsigned*)(row_ptr + NNODES + 1);       // E = 6.4 MB
    int* gcur    = (int*)(colpack + NEDGES);                     // NBUCK
    int* blksum  = gcur + NBUCK;                                 // 128
    int* blkoff  = blksum + 128;                                 // 128
    int* scur    = blkoff + 128;                                 // 1
    float* scal  = (float*)(scur + 1);                           // 2

    (void)hipMemsetAsync(deg, 0, NNODES * sizeof(int), stream);

    k_layer0M<<<1024, 256, 0, stream>>>(x, W0, b0, h0b);
    k_hist   <<<1024, 256, 0, stream>>>(ei, deg);
    k_scan1  <<<SCAN_NB, SCAN_B, 0, stream>>>(deg, row_ptr, blksum);
    k_scan2  <<<1, 128, 0, stream>>>(blksum, blkoff, scur);
    k_scan3  <<<SCAN_NB, SCAN_B, 0, stream>>>(row_ptr, blkoff, gcur);
    k_bin    <<<BIN_BLOCKS, 256, 0, stream>>>(ei, gcur, colpack);
    k_sort   <<<NBUCK, 256, 0, stream>>>(colpack, row_ptr, deg, scur);
    k_agg    <<<4096, 256, 0, stream>>>(h0b, row_ptr, (const int*)colpack, out);
    k_head   <<<1, 256, 0, stream>>>(x, W0, b0, row_ptr, (const int*)colpack, Wm, bm, W1, b1, scal);
    k_gemm   <<<1024, 256, 0, stream>>>(out, Wm, bm, scal, 1);
    k_gemm   <<<1024, 256, 0, stream>>>(out, W1, b1, scal, 2);
}

// Round 10
// 256.635 us; speedup vs baseline: 3.0999x; 1.1690x over previous
//
#include <hip/hip_runtime.h>
#include <math.h>

#define NNODES 100000
#define NEDGES 1600000
#define DD 64
#define EPS 1e-8f

#define NBUCK 1024
#define BW 98
#define BIN_BLOCKS 256
#define BIN_CHUNK ((NEDGES + BIN_BLOCKS - 1) / BIN_BLOCKS)  // 6250
#define BIN_CAP 16
#define SORT_CAP 4096
#define NTILES (NNODES / 16)   // 6250, exact

typedef unsigned short us8 __attribute__((ext_vector_type(8)));
typedef short short8 __attribute__((ext_vector_type(8)));
typedef float f32x4 __attribute__((ext_vector_type(4)));

__device__ __forceinline__ float wave_sum(float v) {
    #pragma unroll
    for (int off = 32; off; off >>= 1) v += __shfl_xor(v, off, 64);
    return v;
}

__device__ __forceinline__ float hinner(float u, float v, float sgn) {
    return wave_sum(sgn * u * v);
}

__device__ __forceinline__ float cross_ratio(float r0, float r1, float r2, float r3, float sgn) {
    float A = hinner(r0, r2, sgn);
    float B = hinner(r1, r3, sgn);
    float C = hinner(r0, r3, sgn);
    float Dv = hinner(r1, r2, sgn);
    return (A * B) / (C * Dv + EPS);
}

__device__ __forceinline__ float restore_scale(float cr_i, float cr_c) {
    float ratio = cr_i / (cr_c + EPS);
    bool cond = (!__builtin_isnan(cr_c)) && (!__builtin_isnan(cr_i)) &&
                (fabsf(cr_c) > EPS) && (fabsf(cr_i) > EPS) && (ratio > EPS);
    float s = 1.0f;
    if (cond) {
        s = sqrtf(fabsf(ratio));
        if (!__builtin_isfinite(s)) s = 1.0f;
    }
    return s;
}

__device__ __forceinline__ unsigned short f2bf(float f) {
    unsigned u = __float_as_uint(f);
    unsigned r = (u + 0x7fffu + ((u >> 16) & 1u)) >> 16;
    return (unsigned short)r;
}

__device__ __forceinline__ float bf2f(unsigned short b) {
    return __uint_as_float(((unsigned)b) << 16);
}

__device__ __forceinline__ float bcast(float v, int lane) {
    return __int_as_float(__builtin_amdgcn_readlane(__float_as_int(v), lane));
}

// load one weight matrix as split-bf16 B fragments: frag (t,h) lane l holds
// W[h*32 + (l>>4)*8 + j][t*16 + (l&15)], j=0..7
__device__ __forceinline__ void load_bfrags(const float* __restrict__ W, int lane,
                                            short8 bhi[4][2], short8 blo[4][2]) {
    int c = lane & 15, q = lane >> 4;
    #pragma unroll
    for (int t = 0; t < 4; t++)
        #pragma unroll
        for (int h = 0; h < 2; h++) {
            short8 hi8, lo8;
            #pragma unroll
            for (int j = 0; j < 8; j++) {
                float w = W[(h * 32 + q * 8 + j) * DD + t * 16 + c];
                unsigned short hb = f2bf(w);
                float r = w - bf2f(hb);
                hi8[j] = (short)hb;
                lo8[j] = (short)f2bf(r);
            }
            bhi[t][h] = hi8;
            blo[t][h] = lo8;
        }
}

// build split-bf16 A fragment from 8 consecutive floats
__device__ __forceinline__ void build_a(const float* p, short8& hi, short8& lo) {
    float4 f0 = *(const float4*)p;
    float4 f1 = *(const float4*)(p + 4);
    float av[8] = {f0.x, f0.y, f0.z, f0.w, f1.x, f1.y, f1.z, f1.w};
    short8 h8, l8;
    #pragma unroll
    for (int j = 0; j < 8; j++) {
        unsigned short hb = f2bf(av[j]);
        float r = av[j] - bf2f(hb);
        h8[j] = (short)hb;
        l8[j] = (short)f2bf(r);
    }
    hi = h8;
    lo = l8;
}

#define MFMA3(cacc, ahi, alo, t, h)                                              \
    cacc = __builtin_amdgcn_mfma_f32_16x16x32_bf16(ahi, bhi[t][h], cacc, 0, 0, 0); \
    cacc = __builtin_amdgcn_mfma_f32_16x16x32_bf16(alo, bhi[t][h], cacc, 0, 0, 0); \
    cacc = __builtin_amdgcn_mfma_f32_16x16x32_bf16(ahi, blo[t][h], cacc, 0, 0, 0);

// layer0 via MFMA: h0b = bf16(normalize(x @ W0 + b0)), 16 rows per wave-tile.
__global__ __launch_bounds__(256, 3) void k_layer0M(const float* __restrict__ x,
                                                    const float* __restrict__ W0,
                                                    const float* __restrict__ b0,
                                                    unsigned short* __restrict__ h0b) {
    int lane = threadIdx.x & 63;
    int c = lane & 15, q = lane >> 4;
    short8 bhi[4][2], blo[4][2];
    load_bfrags(W0, lane, bhi, blo);
    float badd[4];
    #pragma unroll
    for (int t = 0; t < 4; t++) badd[t] = b0[t * 16 + c];
    int wid = (blockIdx.x * 256 + threadIdx.x) >> 6;
    int nw = (gridDim.x * 256) >> 6;
    for (int tile = wid; tile < NTILES; tile += nw) {
        int R = tile * 16;
        f32x4 cc[4] = {{0, 0, 0, 0}, {0, 0, 0, 0}, {0, 0, 0, 0}, {0, 0, 0, 0}};
        #pragma unroll
        for (int h = 0; h < 2; h++) {
            short8 ahi, alo;
            build_a(x + ((size_t)(R + c) << 6) + h * 32 + q * 8, ahi, alo);
            #pragma unroll
            for (int t = 0; t < 4; t++) { MFMA3(cc[t], ahi, alo, t, h); }
        }
        float ss[4];
        #pragma unroll
        for (int r = 0; r < 4; r++) {
            #pragma unroll
            for (int t = 0; t < 4; t++) cc[t][r] += badd[t];
            ss[r] = cc[0][r] * cc[0][r] + cc[1][r] * cc[1][r] +
                    cc[2][r] * cc[2][r] + cc[3][r] * cc[3][r];
        }
        #pragma unroll
        for (int off = 1; off <= 8; off <<= 1) {
            #pragma unroll
            for (int r = 0; r < 4; r++) ss[r] += __shfl_xor(ss[r], off, 64);
        }
        #pragma unroll
        for (int r = 0; r < 4; r++) {
            float sc = 1.0f / (sqrtf(ss[r]) + EPS);
            int row = R + q * 4 + r;
            #pragma unroll
            for (int t = 0; t < 4; t++)
                h0b[(size_t)row * DD + t * 16 + c] = f2bf(cc[t][r] * sc);
        }
    }
}

// fused GEMM + normalize epilogue, in place on `data`.
// mode 1: out = normalize(data@W + b) * scal[0]
// mode 2: out = relu(normalize(data@W + b)) * scal[1]
__global__ __launch_bounds__(256, 3) void k_gemm(float* data,
                                                 const float* __restrict__ W,
                                                 const float* __restrict__ bias,
                                                 const float* __restrict__ scal,
                                                 int mode) {
    int lane = threadIdx.x & 63;
    int c = lane & 15, q = lane >> 4;
    short8 bhi[4][2], blo[4][2];
    load_bfrags(W, lane, bhi, blo);
    float badd[4];
    #pragma unroll
    for (int t = 0; t < 4; t++) badd[t] = bias[t * 16 + c];
    float s = (mode == 1) ? scal[0] : scal[1];
    int wid = (blockIdx.x * 256 + threadIdx.x) >> 6;
    int nw = (gridDim.x * 256) >> 6;
    for (int tile = wid; tile < NTILES; tile += nw) {
        int R = tile * 16;
        f32x4 cc[4] = {{0, 0, 0, 0}, {0, 0, 0, 0}, {0, 0, 0, 0}, {0, 0, 0, 0}};
        #pragma unroll
        for (int h = 0; h < 2; h++) {
            short8 ahi, alo;
            build_a(data + ((size_t)(R + c) << 6) + h * 32 + q * 8, ahi, alo);
            #pragma unroll
            for (int t = 0; t < 4; t++) { MFMA3(cc[t], ahi, alo, t, h); }
        }
        float ss[4];
        #pragma unroll
        for (int r = 0; r < 4; r++) {
            #pragma unroll
            for (int t = 0; t < 4; t++) cc[t][r] += badd[t];
            ss[r] = cc[0][r] * cc[0][r] + cc[1][r] * cc[1][r] +
                    cc[2][r] * cc[2][r] + cc[3][r] * cc[3][r];
        }
        #pragma unroll
        for (int off = 1; off <= 8; off <<= 1) {
            #pragma unroll
            for (int r = 0; r < 4; r++) ss[r] += __shfl_xor(ss[r], off, 64);
        }
        #pragma unroll
        for (int r = 0; r < 4; r++) {
            float sc = 1.0f / (sqrtf(ss[r]) + EPS);
            int row = R + q * 4 + r;
            #pragma unroll
            for (int t = 0; t < 4; t++) {
                float v = cc[t][r] * sc;
                if (mode == 2) v = fmaxf(v, 0.0f);
                data[(size_t)row * DD + t * 16 + c] = v * s;
            }
        }
    }
}

// bucket-level histogram (LDS-staged; only NBUCK counters -> tiny atomic traffic)
__global__ __launch_bounds__(256) void k_bhist(const int* __restrict__ ei,
                                               int* __restrict__ bhist) {
    __shared__ int h[NBUCK];
    for (int i = threadIdx.x; i < NBUCK; i += 256) h[i] = 0;
    __syncthreads();
    int tid = blockIdx.x * 256 + threadIdx.x;
    int stride = gridDim.x * 256;
    for (int e = tid; e < NEDGES; e += stride)
        atomicAdd(&h[(unsigned)ei[NEDGES + e] / BW], 1);
    __syncthreads();
    for (int i = threadIdx.x; i < NBUCK; i += 256)
        if (h[i]) atomicAdd(&bhist[i], h[i]);
}

// single block: exclusive scan of 1024 bucket counts -> bstart, gcur;
// init scratch cursor and row_ptr[N].
__global__ __launch_bounds__(NBUCK) void k_scan1024(const int* __restrict__ bhist,
                                                    int* __restrict__ bstart,
                                                    int* __restrict__ gcur,
                                                    int* __restrict__ scratch_cur,
                                                    int* __restrict__ row_ptr) {
    __shared__ int s[NBUCK];
    int t = threadIdx.x;
    int v = bhist[t];
    s[t] = v;
    __syncthreads();
    for (int off = 1; off < NBUCK; off <<= 1) {
        int u = (t >= off) ? s[t - off] : 0;
        __syncthreads();
        s[t] += u;
        __syncthreads();
    }
    bstart[t] = s[t] - v;
    gcur[t] = s[t] - v;
    if (t == 0) {
        scratch_cur[0] = 0;
        row_ptr[NNODES] = NEDGES;
    }
}

// bin edges into per-bucket dense runs inside their bucket windows.
__global__ __launch_bounds__(256) void k_bin(const int* __restrict__ ei,
                                             int* __restrict__ gcur,
                                             unsigned* __restrict__ colpack) {
    __shared__ unsigned stag[NBUCK * BIN_CAP];
    __shared__ int lcnt[NBUCK];
    int t = threadIdx.x;
    for (int i = t; i < NBUCK; i += 256) lcnt[i] = 0;
    __syncthreads();
    int lo = blockIdx.x * BIN_CHUNK;
    int hi = lo + BIN_CHUNK; if (hi > NEDGES) hi = NEDGES;
    for (int e = lo + t; e < hi; e += 256) {
        int d = ei[NEDGES + e];
        int s = ei[e];
        unsigned b = (unsigned)d / BW;
        unsigned dl = (unsigned)d - b * BW;
        unsigned pk = ((unsigned)s << 8) | dl;
        int slot = atomicAdd(&lcnt[b], 1);
        if (slot < BIN_CAP) {
            stag[b * BIN_CAP + slot] = pk;
        } else {
            colpack[atomicAdd(&gcur[b], 1)] = pk;
        }
    }
    __syncthreads();
    for (int b = t; b < NBUCK; b += 256) {
        int cnt = lcnt[b];
        if (cnt > BIN_CAP) cnt = BIN_CAP;
        if (cnt > 0) {
            int base = atomicAdd(&gcur[b], cnt);
            for (int i = 0; i < cnt; i++)
                colpack[base + i] = stag[b * BIN_CAP + i];
        }
    }
}

// one block per bucket: count per-node degrees from the bucket run, prefix-sum,
// WRITE row_ptr for this bucket's nodes, then LDS counting-sort the run into
// CSR order (colpack becomes plain src). All reads precede all writes.
__global__ __launch_bounds__(256) void k_sortD(unsigned* __restrict__ colpack,
                                               const int* __restrict__ bstart,
                                               const int* __restrict__ bhist,
                                               int* __restrict__ row_ptr,
                                               int* __restrict__ scratch,
                                               int* __restrict__ scratch_cur) {
    __shared__ int cnt[BW];
    __shared__ int pre[BW];
    int b = blockIdx.x;
    int t = threadIdx.x;
    int nlo = b * BW; if (nlo > NNODES) nlo = NNODES;
    int nhi = nlo + BW; if (nhi > NNODES) nhi = NNODES;
    int base = bstart[b];
    int n = bhist[b];
    for (int i = t; i < BW; i += 256) cnt[i] = 0;
    __syncthreads();
    if (n <= SORT_CAP) {
        unsigned ent[SORT_CAP / 256];
        int c = 0;
        for (int i = t; i < n; i += 256) {
            ent[c] = colpack[base + i];
            atomicAdd(&cnt[ent[c] & 255u], 1);
            c++;
        }
        __syncthreads();
        if (t == 0) {
            int s = 0;
            for (int i = 0; i < BW; i++) { pre[i] = s; s += cnt[i]; }
        }
        __syncthreads();
        for (int i = t; i < nhi - nlo; i += 256)
            row_ptr[nlo + i] = base + pre[i];
        for (int i = t; i < BW; i += 256) cnt[i] = pre[i];
        __syncthreads();
        for (int j = 0; j < c; j++) {
            int pos = atomicAdd(&cnt[ent[j] & 255u], 1);
            colpack[base + pos] = ent[j] >> 8;
        }
    } else {
        // overflow fallback (not hit at mean bucket size ~1562): via global scratch
        int sb = 0;
        if (t == 0) sb = atomicAdd(scratch_cur, n);
        sb = __shfl(sb, 0, 64);
        sb = __builtin_amdgcn_readfirstlane(sb);
        for (int i = t; i < n; i += 256) {
            unsigned pk = colpack[base + i];
            scratch[sb + i] = (int)pk;
            atomicAdd(&cnt[pk & 255u], 1);
        }
        __syncthreads();
        if (t == 0) {
            int s = 0;
            for (int i = 0; i < BW; i++) { pre[i] = s; s += cnt[i]; }
        }
        __syncthreads();
        for (int i = t; i < nhi - nlo; i += 256)
            row_ptr[nlo + i] = base + pre[i];
        for (int i = t; i < BW; i += 256) cnt[i] = pre[i];
        __syncthreads();
        for (int i = t; i < n; i += 256) {
            unsigned pk = (unsigned)scratch[sb + i];
            int p = atomicAdd(&cnt[pk & 255u], 1);
            colpack[base + p] = pk >> 8;
        }
    }
}

// pure gather-mean over CSR: one wave per dst row, 8 edges in flight.
__global__ __launch_bounds__(256) void k_agg(const unsigned short* __restrict__ h0b,
                                             const int* __restrict__ row_ptr,
                                             const int* __restrict__ col,
                                             float* __restrict__ agg) {
    int lane = threadIdx.x & 63;
    int q = lane & 7;
    int g = lane >> 3;
    int wid = (blockIdx.x * 256 + threadIdx.x) >> 6;
    int nw = (gridDim.x * 256) >> 6;
    for (int row = wid; row < NNODES; row += nw) {
        int start = row_ptr[row], end = row_ptr[row + 1];
        float s[8] = {0, 0, 0, 0, 0, 0, 0, 0};
        for (int cb = start; cb < end; cb += 64) {
            int c = (cb + lane < end) ? col[cb + lane] : 0;
            int m = end - cb; if (m > 64) m = 64;
            for (int j = 0; j < m; j += 8) {
                int e = j + g;
                bool val = e < m;
                int esafe = val ? e : 0;
                int src = __shfl(c, esafe, 64);
                us8 u = *(const us8*)(h0b + (size_t)src * DD + q * 8);
                float f = val ? 1.0f : 0.0f;
                #pragma unroll
                for (int i = 0; i < 8; i++)
                    s[i] = fmaf(f, bf2f(u[i]), s[i]);
            }
        }
        #pragma unroll
        for (int i = 0; i < 8; i++) {
            s[i] += __shfl_xor(s[i], 8, 64);
            s[i] += __shfl_xor(s[i], 16, 64);
            s[i] += __shfl_xor(s[i], 32, 64);
        }
        if (g == 0) {
            float inv = 1.0f / fmaxf((float)(end - start), 1.0f);
            float4* dst = (float4*)(agg + (size_t)row * DD + q * 8);
            float4 o0 = {s[0] * inv, s[1] * inv, s[2] * inv, s[3] * inv};
            float4 o1 = {s[4] * inv, s[5] * inv, s[6] * inv, s[7] * inv};
            dst[0] = o0;
            dst[1] = o1;
        }
    }
}

// head kernel (4 waves): rows 0..3 through the full pipeline in fp32 -> s1, s2.
__global__ __launch_bounds__(256) void k_head(const float* __restrict__ x,
                       const float* __restrict__ W0, const float* __restrict__ b0,
                       const int* __restrict__ row_ptr, const int* __restrict__ col,
                       const float* __restrict__ Wm, const float* __restrict__ bm,
                       const float* __restrict__ W1, const float* __restrict__ b1,
                       float* __restrict__ scal) {
    __shared__ float hs[4][DD];
    __shared__ float h2s[4][DD];
    __shared__ float frs[4][DD];
    int lane = threadIdx.x & 63;
    int w = threadIdx.x >> 6;
    float sgn = (lane == 63) ? -1.0f : 1.0f;

    float w0[DD];
    #pragma unroll
    for (int k = 0; k < DD; k++) w0[k] = W0[k * DD + lane];
    float b0v = b0[lane];

    auto h0row = [&](int r) -> float {
        float xv = x[(size_t)r * DD + lane];
        float acc = b0v;
        #pragma unroll
        for (int k = 0; k < DD; k++)
            acc = fmaf(bcast(xv, k), w0[k], acc);
        float n = sqrtf(wave_sum(acc * acc));
        return acc / (n + EPS);
    };

    hs[w][lane] = h0row(w);

    int start = row_ptr[w], end = row_ptr[w + 1];
    float sum = 0.0f;
    for (int i = start; i < end; i++) sum += h0row(col[i]);
    float av = sum / fmaxf((float)(end - start), 1.0f);
    float acc = bm[lane];
    #pragma unroll
    for (int k = 0; k < DD; k++)
        acc = fmaf(bcast(av, k), Wm[k * DD + lane], acc);
    float n = sqrtf(wave_sum(acc * acc));
    h2s[w][lane] = acc / (n + EPS);
    __syncthreads();

    float cr_init = cross_ratio(x[lane], x[DD + lane], x[2 * DD + lane], x[3 * DD + lane], sgn);
    float cr0 = cross_ratio(hs[0][lane], hs[1][lane], hs[2][lane], hs[3][lane], sgn);
    float cr_cur = cross_ratio(h2s[0][lane], h2s[1][lane], h2s[2][lane], h2s[3][lane], sgn);
    float s1 = restore_scale(cr0, cr_cur);

    float hv = h2s[w][lane] * s1;
    float acc2 = b1[lane];
    #pragma unroll
    for (int k = 0; k < DD; k++)
        acc2 = fmaf(bcast(hv, k), W1[k * DD + lane], acc2);
    n = sqrtf(wave_sum(acc2 * acc2));
    frs[w][lane] = fmaxf(acc2 / (n + EPS), 0.0f);
    __syncthreads();

    if (w == 0) {
        float cr2 = cross_ratio(frs[0][lane], frs[1][lane], frs[2][lane], frs[3][lane], sgn);
        float s2 = restore_scale(cr_init, cr2);
        if (lane == 0) { scal[0] = s1; scal[1] = s2; }
    }
}

extern "C" void kernel_launch(void* const* d_in, const int* in_sizes, int n_in,
                              void* d_out, int out_size, void* d_ws, size_t ws_size,
                              hipStream_t stream) {
    const float* x  = (const float*)d_in[0];
    const int*   ei = (const int*)d_in[1];
    const float* W0 = (const float*)d_in[2];
    const float* b0 = (const float*)d_in[3];
    const float* Wm = (const float*)d_in[4];
    const float* bm = (const float*)d_in[5];
    const float* W1 = (const float*)d_in[6];
    const float* b1 = (const float*)d_in[7];
    float* out = (float*)d_out;

    // ws layout (~20.0 MB)
    unsigned short* h0b = (unsigned short*)d_ws;                 // N*64 bf16 = 12.8 MB
    int* scratch = (int*)(h0b + (size_t)NNODES * DD);            // N (sort overflow scratch)
    int* row_ptr = scratch + NNODES;                             // N+1
    unsigned* colpack = (unsigned*)(row_ptr + NNODES + 1);       // E = 6.4 MB
    int* bhist  = (int*)(colpack + NEDGES);                      // 1024
    int* bstart = bhist + NBUCK;                                 // 1024
    int* gcur   = bstart + NBUCK;                                // 1024
    int* scur   = gcur + NBUCK;                                  // 1
    float* scal = (float*)(scur + 1);                            // 2

    (void)hipMemsetAsync(bhist, 0, NBUCK * sizeof(int), stream);

    k_layer0M <<<1024, 256, 0, stream>>>(x, W0, b0, h0b);
    k_bhist   <<<512, 256, 0, stream>>>(ei, bhist);
    k_scan1024<<<1, NBUCK, 0, stream>>>(bhist, bstart, gcur, scur, row_ptr);
    k_bin     <<<BIN_BLOCKS, 256, 0, stream>>>(ei, gcur, colpack);
    k_sortD   <<<NBUCK, 256, 0, stream>>>(colpack, bstart, bhist, row_ptr, scratch, scur);
    k_agg     <<<4096, 256, 0, stream>>>(h0b, row_ptr, (const int*)colpack, out);
    k_head    <<<1, 256, 0, stream>>>(x, W0, b0, row_ptr, (const int*)colpack, Wm, bm, W1, b1, scal);
    k_gemm    <<<1024, 256, 0, stream>>>(out, Wm, bm, scal, 1);
    k_gemm    <<<1024, 256, 0, stream>>>(out, W1, b1, scal, 2);
}

// Round 11
// 247.345 us; speedup vs baseline: 3.2163x; 1.0376x over previous
//
#include <hip/hip_runtime.h>
#include <math.h>

#define NNODES 100000
#define NEDGES 1600000
#define DD 64
#define EPS 1e-8f

#define NBUCK 1024
#define BW 98
#define BIN_BLOCKS 256
#define BIN_CHUNK ((NEDGES + BIN_BLOCKS - 1) / BIN_BLOCKS)  // 6250
#define BIN_CAP 16
#define SORT_CAP 4096
#define NTILES (NNODES / 16)   // 6250, exact
#define CAP4 512
#define TSTR 68                // LDS transpose row stride (floats), breaks bank aliasing

typedef unsigned short us8 __attribute__((ext_vector_type(8)));
typedef short short8 __attribute__((ext_vector_type(8)));
typedef float f32x4 __attribute__((ext_vector_type(4)));

__device__ __forceinline__ float wave_sum(float v) {
    #pragma unroll
    for (int off = 32; off; off >>= 1) v += __shfl_xor(v, off, 64);
    return v;
}

__device__ __forceinline__ float hinner(float u, float v, float sgn) {
    return wave_sum(sgn * u * v);
}

__device__ __forceinline__ float cross_ratio(float r0, float r1, float r2, float r3, float sgn) {
    float A = hinner(r0, r2, sgn);
    float B = hinner(r1, r3, sgn);
    float C = hinner(r0, r3, sgn);
    float Dv = hinner(r1, r2, sgn);
    return (A * B) / (C * Dv + EPS);
}

__device__ __forceinline__ float restore_scale(float cr_i, float cr_c) {
    float ratio = cr_i / (cr_c + EPS);
    bool cond = (!__builtin_isnan(cr_c)) && (!__builtin_isnan(cr_i)) &&
                (fabsf(cr_c) > EPS) && (fabsf(cr_i) > EPS) && (ratio > EPS);
    float s = 1.0f;
    if (cond) {
        s = sqrtf(fabsf(ratio));
        if (!__builtin_isfinite(s)) s = 1.0f;
    }
    return s;
}

__device__ __forceinline__ unsigned short f2bf(float f) {
    unsigned u = __float_as_uint(f);
    unsigned r = (u + 0x7fffu + ((u >> 16) & 1u)) >> 16;
    return (unsigned short)r;
}

__device__ __forceinline__ float bf2f(unsigned short b) {
    return __uint_as_float(((unsigned)b) << 16);
}

__device__ __forceinline__ float bcast(float v, int lane) {
    return __int_as_float(__builtin_amdgcn_readlane(__float_as_int(v), lane));
}

// load one weight matrix as split-bf16 B fragments: frag (t,h) lane l holds
// W[h*32 + (l>>4)*8 + j][t*16 + (l&15)], j=0..7
__device__ __forceinline__ void load_bfrags(const float* __restrict__ W, int lane,
                                            short8 bhi[4][2], short8 blo[4][2]) {
    int c = lane & 15, q = lane >> 4;
    #pragma unroll
    for (int t = 0; t < 4; t++)
        #pragma unroll
        for (int h = 0; h < 2; h++) {
            short8 hi8, lo8;
            #pragma unroll
            for (int j = 0; j < 8; j++) {
                float w = W[(h * 32 + q * 8 + j) * DD + t * 16 + c];
                unsigned short hb = f2bf(w);
                float r = w - bf2f(hb);
                hi8[j] = (short)hb;
                lo8[j] = (short)f2bf(r);
            }
            bhi[t][h] = hi8;
            blo[t][h] = lo8;
        }
}

// build split-bf16 A fragment from 8 floats
__device__ __forceinline__ void build_a8(const float av[8], short8& hi, short8& lo) {
    short8 h8, l8;
    #pragma unroll
    for (int j = 0; j < 8; j++) {
        unsigned short hb = f2bf(av[j]);
        float r = av[j] - bf2f(hb);
        h8[j] = (short)hb;
        l8[j] = (short)f2bf(r);
    }
    hi = h8;
    lo = l8;
}

__device__ __forceinline__ void build_a(const float* p, short8& hi, short8& lo) {
    float4 f0 = *(const float4*)p;
    float4 f1 = *(const float4*)(p + 4);
    float av[8] = {f0.x, f0.y, f0.z, f0.w, f1.x, f1.y, f1.z, f1.w};
    build_a8(av, hi, lo);
}

#define MFMA3(cacc, ahi, alo, BH, BL, t, h)                                      \
    cacc = __builtin_amdgcn_mfma_f32_16x16x32_bf16(ahi, BH[t][h], cacc, 0, 0, 0); \
    cacc = __builtin_amdgcn_mfma_f32_16x16x32_bf16(alo, BH[t][h], cacc, 0, 0, 0); \
    cacc = __builtin_amdgcn_mfma_f32_16x16x32_bf16(ahi, BL[t][h], cacc, 0, 0, 0);

// fused: blocks [0,512) bucket-histogram; blocks [512,1536) layer0 MFMA.
__global__ __launch_bounds__(256, 3) void k_l0h(const float* __restrict__ x,
                                                const float* __restrict__ W0,
                                                const float* __restrict__ b0,
                                                unsigned short* __restrict__ h0b,
                                                const int* __restrict__ ei,
                                                int* __restrict__ bhist) {
    __shared__ int h[NBUCK];
    if (blockIdx.x < 512) {
        for (int i = threadIdx.x; i < NBUCK; i += 256) h[i] = 0;
        __syncthreads();
        int tid = blockIdx.x * 256 + threadIdx.x;
        int stride = 512 * 256;
        for (int e = tid; e < NEDGES; e += stride)
            atomicAdd(&h[(unsigned)ei[NEDGES + e] / BW], 1);
        __syncthreads();
        for (int i = threadIdx.x; i < NBUCK; i += 256)
            if (h[i]) atomicAdd(&bhist[i], h[i]);
        return;
    }
    int bid = blockIdx.x - 512;
    int lane = threadIdx.x & 63;
    int c = lane & 15, q = lane >> 4;
    short8 bhi[4][2], blo[4][2];
    load_bfrags(W0, lane, bhi, blo);
    float badd[4];
    #pragma unroll
    for (int t = 0; t < 4; t++) badd[t] = b0[t * 16 + c];
    int wid = (bid * 256 + threadIdx.x) >> 6;
    int nw = (1024 * 256) >> 6;
    for (int tile = wid; tile < NTILES; tile += nw) {
        int R = tile * 16;
        f32x4 cc[4] = {{0, 0, 0, 0}, {0, 0, 0, 0}, {0, 0, 0, 0}, {0, 0, 0, 0}};
        #pragma unroll
        for (int hh = 0; hh < 2; hh++) {
            short8 ahi, alo;
            build_a(x + ((size_t)(R + c) << 6) + hh * 32 + q * 8, ahi, alo);
            #pragma unroll
            for (int t = 0; t < 4; t++) { MFMA3(cc[t], ahi, alo, bhi, blo, t, hh); }
        }
        float ss[4];
        #pragma unroll
        for (int r = 0; r < 4; r++) {
            #pragma unroll
            for (int t = 0; t < 4; t++) cc[t][r] += badd[t];
            ss[r] = cc[0][r] * cc[0][r] + cc[1][r] * cc[1][r] +
                    cc[2][r] * cc[2][r] + cc[3][r] * cc[3][r];
        }
        #pragma unroll
        for (int off = 1; off <= 8; off <<= 1) {
            #pragma unroll
            for (int r = 0; r < 4; r++) ss[r] += __shfl_xor(ss[r], off, 64);
        }
        #pragma unroll
        for (int r = 0; r < 4; r++) {
            float sc = 1.0f / (sqrtf(ss[r]) + EPS);
            int row = R + q * 4 + r;
            #pragma unroll
            for (int t = 0; t < 4; t++)
                h0b[(size_t)row * DD + t * 16 + c] = f2bf(cc[t][r] * sc);
        }
    }
}

// single block: exclusive scan of 1024 bucket counts -> bstart, gcur; init misc.
__global__ __launch_bounds__(NBUCK) void k_scan1024(const int* __restrict__ bhist,
                                                    int* __restrict__ bstart,
                                                    int* __restrict__ gcur,
                                                    int* __restrict__ scratch_cur,
                                                    int* __restrict__ row_ptr) {
    __shared__ int s[NBUCK];
    int t = threadIdx.x;
    int v = bhist[t];
    s[t] = v;
    __syncthreads();
    for (int off = 1; off < NBUCK; off <<= 1) {
        int u = (t >= off) ? s[t - off] : 0;
        __syncthreads();
        s[t] += u;
        __syncthreads();
    }
    bstart[t] = s[t] - v;
    gcur[t] = s[t] - v;
    if (t == 0) {
        scratch_cur[0] = 0;
        row_ptr[NNODES] = NEDGES;
    }
}

// bin edges into per-bucket dense runs; also collect rows 0..3 neighbor lists.
__global__ __launch_bounds__(256) void k_bin(const int* __restrict__ ei,
                                             int* __restrict__ gcur,
                                             unsigned* __restrict__ colpack,
                                             int* __restrict__ cnt4,
                                             int* __restrict__ list4) {
    __shared__ unsigned stag[NBUCK * BIN_CAP];
    __shared__ int lcnt[NBUCK];
    int t = threadIdx.x;
    for (int i = t; i < NBUCK; i += 256) lcnt[i] = 0;
    __syncthreads();
    int lo = blockIdx.x * BIN_CHUNK;
    int hi = lo + BIN_CHUNK; if (hi > NEDGES) hi = NEDGES;
    for (int e = lo + t; e < hi; e += 256) {
        int d = ei[NEDGES + e];
        int s = ei[e];
        if ((unsigned)d < 4u) {
            int p = atomicAdd(&cnt4[d], 1);
            if (p < CAP4) list4[d * CAP4 + p] = s;
        }
        unsigned b = (unsigned)d / BW;
        unsigned dl = (unsigned)d - b * BW;
        unsigned pk = ((unsigned)s << 8) | dl;
        int slot = atomicAdd(&lcnt[b], 1);
        if (slot < BIN_CAP) {
            stag[b * BIN_CAP + slot] = pk;
        } else {
            colpack[atomicAdd(&gcur[b], 1)] = pk;
        }
    }
    __syncthreads();
    for (int b = t; b < NBUCK; b += 256) {
        int cnt = lcnt[b];
        if (cnt > BIN_CAP) cnt = BIN_CAP;
        if (cnt > 0) {
            int base = atomicAdd(&gcur[b], cnt);
            for (int i = 0; i < cnt; i++)
                colpack[base + i] = stag[b * BIN_CAP + i];
        }
    }
}

// blocks [0,NBUCK): per-bucket degree count + row_ptr write + counting sort.
// block NBUCK: head — rows 0..3 full pipeline in fp32 -> scal.
__global__ __launch_bounds__(256, 4) void k_sortDH(unsigned* __restrict__ colpack,
                                                   const int* __restrict__ bstart,
                                                   const int* __restrict__ bhist,
                                                   int* __restrict__ row_ptr,
                                                   int* __restrict__ scratch,
                                                   int* __restrict__ scratch_cur,
                                                   const float* __restrict__ x,
                                                   const float* __restrict__ W0,
                                                   const float* __restrict__ b0,
                                                   const int* __restrict__ cnt4,
                                                   const int* __restrict__ list4,
                                                   const float* __restrict__ Wm,
                                                   const float* __restrict__ bm,
                                                   const float* __restrict__ W1,
                                                   const float* __restrict__ b1,
                                                   float* __restrict__ scal) {
    __shared__ int cnt[BW];
    __shared__ int pre[BW];
    __shared__ float hs[4][DD];
    __shared__ float h2s[4][DD];
    __shared__ float frs[4][DD];
    int t = threadIdx.x;
    if (blockIdx.x == NBUCK) {
        // ---- head ----
        int lane = t & 63;
        int w = t >> 6;
        float sgn = (lane == 63) ? -1.0f : 1.0f;
        float w0[DD];
        #pragma unroll
        for (int k = 0; k < DD; k++) w0[k] = W0[k * DD + lane];
        float b0v = b0[lane];
        auto h0row = [&](int r) -> float {
            float xv = x[(size_t)r * DD + lane];
            float acc = b0v;
            #pragma unroll
            for (int k = 0; k < DD; k++)
                acc = fmaf(bcast(xv, k), w0[k], acc);
            float n = sqrtf(wave_sum(acc * acc));
            return acc / (n + EPS);
        };
        hs[w][lane] = h0row(w);
        int full = cnt4[w];
        int cl = full; if (cl > CAP4) cl = CAP4;
        float sum = 0.0f;
        for (int i = 0; i < cl; i++) sum += h0row(list4[w * CAP4 + i]);
        float av = sum / fmaxf((float)full, 1.0f);
        float acc = bm[lane];
        #pragma unroll
        for (int k = 0; k < DD; k++)
            acc = fmaf(bcast(av, k), Wm[k * DD + lane], acc);
        float n = sqrtf(wave_sum(acc * acc));
        h2s[w][lane] = acc / (n + EPS);
        __syncthreads();
        float cr_init = cross_ratio(x[lane], x[DD + lane], x[2 * DD + lane], x[3 * DD + lane], sgn);
        float cr0 = cross_ratio(hs[0][lane], hs[1][lane], hs[2][lane], hs[3][lane], sgn);
        float cr_cur = cross_ratio(h2s[0][lane], h2s[1][lane], h2s[2][lane], h2s[3][lane], sgn);
        float s1 = restore_scale(cr0, cr_cur);
        float hv = h2s[w][lane] * s1;
        float acc2 = b1[lane];
        #pragma unroll
        for (int k = 0; k < DD; k++)
            acc2 = fmaf(bcast(hv, k), W1[k * DD + lane], acc2);
        n = sqrtf(wave_sum(acc2 * acc2));
        frs[w][lane] = fmaxf(acc2 / (n + EPS), 0.0f);
        __syncthreads();
        if (w == 0) {
            float cr2 = cross_ratio(frs[0][lane], frs[1][lane], frs[2][lane], frs[3][lane], sgn);
            float s2 = restore_scale(cr_init, cr2);
            if (lane == 0) { scal[0] = s1; scal[1] = s2; }
        }
        return;
    }
    // ---- per-bucket sort + row_ptr ----
    int b = blockIdx.x;
    int nlo = b * BW; if (nlo > NNODES) nlo = NNODES;
    int nhi = nlo + BW; if (nhi > NNODES) nhi = NNODES;
    int base = bstart[b];
    int n = bhist[b];
    for (int i = t; i < BW; i += 256) cnt[i] = 0;
    __syncthreads();
    if (n <= SORT_CAP) {
        unsigned ent[SORT_CAP / 256];
        int c = 0;
        for (int i = t; i < n; i += 256) {
            ent[c] = colpack[base + i];
            atomicAdd(&cnt[ent[c] & 255u], 1);
            c++;
        }
        __syncthreads();
        if (t == 0) {
            int s = 0;
            for (int i = 0; i < BW; i++) { pre[i] = s; s += cnt[i]; }
        }
        __syncthreads();
        for (int i = t; i < nhi - nlo; i += 256)
            row_ptr[nlo + i] = base + pre[i];
        for (int i = t; i < BW; i += 256) cnt[i] = pre[i];
        __syncthreads();
        for (int j = 0; j < c; j++) {
            int pos = atomicAdd(&cnt[ent[j] & 255u], 1);
            colpack[base + pos] = ent[j] >> 8;
        }
    } else {
        int sb = 0;
        if (t == 0) sb = atomicAdd(scratch_cur, n);
        sb = __shfl(sb, 0, 64);
        sb = __builtin_amdgcn_readfirstlane(sb);
        for (int i = t; i < n; i += 256) {
            unsigned pk = colpack[base + i];
            scratch[sb + i] = (int)pk;
            atomicAdd(&cnt[pk & 255u], 1);
        }
        __syncthreads();
        if (t == 0) {
            int s = 0;
            for (int i = 0; i < BW; i++) { pre[i] = s; s += cnt[i]; }
        }
        __syncthreads();
        for (int i = t; i < nhi - nlo; i += 256)
            row_ptr[nlo + i] = base + pre[i];
        for (int i = t; i < BW; i += 256) cnt[i] = pre[i];
        __syncthreads();
        for (int i = t; i < n; i += 256) {
            unsigned pk = (unsigned)scratch[sb + i];
            int p = atomicAdd(&cnt[pk & 255u], 1);
            colpack[base + p] = pk >> 8;
        }
    }
}

// pure gather-mean over CSR: one wave per dst row, 8 edges in flight.
__global__ __launch_bounds__(256) void k_agg(const unsigned short* __restrict__ h0b,
                                             const int* __restrict__ row_ptr,
                                             const int* __restrict__ col,
                                             float* __restrict__ agg) {
    int lane = threadIdx.x & 63;
    int q = lane & 7;
    int g = lane >> 3;
    int wid = (blockIdx.x * 256 + threadIdx.x) >> 6;
    int nw = (gridDim.x * 256) >> 6;
    for (int row = wid; row < NNODES; row += nw) {
        int start = row_ptr[row], end = row_ptr[row + 1];
        float s[8] = {0, 0, 0, 0, 0, 0, 0, 0};
        for (int cb = start; cb < end; cb += 64) {
            int c = (cb + lane < end) ? col[cb + lane] : 0;
            int m = end - cb; if (m > 64) m = 64;
            for (int j = 0; j < m; j += 8) {
                int e = j + g;
                bool val = e < m;
                int esafe = val ? e : 0;
                int src = __shfl(c, esafe, 64);
                us8 u = *(const us8*)(h0b + (size_t)src * DD + q * 8);
                float f = val ? 1.0f : 0.0f;
                #pragma unroll
                for (int i = 0; i < 8; i++)
                    s[i] = fmaf(f, bf2f(u[i]), s[i]);
            }
        }
        #pragma unroll
        for (int i = 0; i < 8; i++) {
            s[i] += __shfl_xor(s[i], 8, 64);
            s[i] += __shfl_xor(s[i], 16, 64);
            s[i] += __shfl_xor(s[i], 32, 64);
        }
        if (g == 0) {
            float inv = 1.0f / fmaxf((float)(end - start), 1.0f);
            float4* dst = (float4*)(agg + (size_t)row * DD + q * 8);
            float4 o0 = {s[0] * inv, s[1] * inv, s[2] * inv, s[3] * inv};
            float4 o1 = {s[4] * inv, s[5] * inv, s[6] * inv, s[7] * inv};
            dst[0] = o0;
            dst[1] = o1;
        }
    }
}

// both GEMMs fused, in place on `data` (=agg):
// H = s1*normalize(data@Wm+bm); out = s2*relu(normalize(H@W1+b1)).
// C-layout -> A-layout transpose via per-wave padded LDS tile (same-wave, no barrier).
__global__ __launch_bounds__(256, 2) void k_gemm2(float* data,
                                                  const float* __restrict__ Wm,
                                                  const float* __restrict__ bm,
                                                  const float* __restrict__ W1,
                                                  const float* __restrict__ b1,
                                                  const float* __restrict__ scal) {
    __shared__ float tsm[4][16 * TSTR];
    int tid = threadIdx.x;
    int wv = tid >> 6, lane = tid & 63;
    int c = lane & 15, q = lane >> 4;
    short8 bhiM[4][2], bloM[4][2], bhi1[4][2], blo1[4][2];
    load_bfrags(Wm, lane, bhiM, bloM);
    load_bfrags(W1, lane, bhi1, blo1);
    float bmv[4], b1v[4];
    #pragma unroll
    for (int t = 0; t < 4; t++) { bmv[t] = bm[t * 16 + c]; b1v[t] = b1[t * 16 + c]; }
    float s1 = scal[0], s2 = scal[1];
    int wid = (blockIdx.x * 256 + tid) >> 6;
    int nw = (gridDim.x * 256) >> 6;
    for (int tile = wid; tile < NTILES; tile += nw) {
        int R = tile * 16;
        // GEMM1
        f32x4 cc[4] = {{0, 0, 0, 0}, {0, 0, 0, 0}, {0, 0, 0, 0}, {0, 0, 0, 0}};
        #pragma unroll
        for (int hh = 0; hh < 2; hh++) {
            short8 ahi, alo;
            build_a(data + ((size_t)(R + c) << 6) + hh * 32 + q * 8, ahi, alo);
            #pragma unroll
            for (int t = 0; t < 4; t++) { MFMA3(cc[t], ahi, alo, bhiM, bloM, t, hh); }
        }
        float ss[4];
        #pragma unroll
        for (int r = 0; r < 4; r++) {
            #pragma unroll
            for (int t = 0; t < 4; t++) cc[t][r] += bmv[t];
            ss[r] = cc[0][r] * cc[0][r] + cc[1][r] * cc[1][r] +
                    cc[2][r] * cc[2][r] + cc[3][r] * cc[3][r];
        }
        #pragma unroll
        for (int off = 1; off <= 8; off <<= 1) {
            #pragma unroll
            for (int r = 0; r < 4; r++) ss[r] += __shfl_xor(ss[r], off, 64);
        }
        // H -> LDS (C-layout scatter)
        #pragma unroll
        for (int r = 0; r < 4; r++) {
            float sc = s1 / (sqrtf(ss[r]) + EPS);
            #pragma unroll
            for (int t = 0; t < 4; t++)
                tsm[wv][(q * 4 + r) * TSTR + t * 16 + c] = cc[t][r] * sc;
        }
        // GEMM2: A-layout reads (row=c, ch=q*8..q*8+7), same wave -> ordered
        f32x4 c2[4] = {{0, 0, 0, 0}, {0, 0, 0, 0}, {0, 0, 0, 0}, {0, 0, 0, 0}};
        #pragma unroll
        for (int hh = 0; hh < 2; hh++) {
            const float* p = &tsm[wv][c * TSTR + hh * 32 + q * 8];
            float av[8];
            #pragma unroll
            for (int j = 0; j < 8; j++) av[j] = p[j];
            short8 ahi, alo;
            build_a8(av, ahi, alo);
            #pragma unroll
            for (int t = 0; t < 4; t++) { MFMA3(c2[t], ahi, alo, bhi1, blo1, t, hh); }
        }
        #pragma unroll
        for (int r = 0; r < 4; r++) {
            #pragma unroll
            for (int t = 0; t < 4; t++) c2[t][r] += b1v[t];
            ss[r] = c2[0][r] * c2[0][r] + c2[1][r] * c2[1][r] +
                    c2[2][r] * c2[2][r] + c2[3][r] * c2[3][r];
        }
        #pragma unroll
        for (int off = 1; off <= 8; off <<= 1) {
            #pragma unroll
            for (int r = 0; r < 4; r++) ss[r] += __shfl_xor(ss[r], off, 64);
        }
        #pragma unroll
        for (int r = 0; r < 4; r++) {
            float sc = 1.0f / (sqrtf(ss[r]) + EPS);
            int row = R + q * 4 + r;
            #pragma unroll
            for (int t = 0; t < 4; t++)
                data[(size_t)row * DD + t * 16 + c] = fmaxf(c2[t][r] * sc, 0.0f) * s2;
        }
    }
}

extern "C" void kernel_launch(void* const* d_in, const int* in_sizes, int n_in,
                              void* d_out, int out_size, void* d_ws, size_t ws_size,
                              hipStream_t stream) {
    const float* x  = (const float*)d_in[0];
    const int*   ei = (const int*)d_in[1];
    const float* W0 = (const float*)d_in[2];
    const float* b0 = (const float*)d_in[3];
    const float* Wm = (const float*)d_in[4];
    const float* bm = (const float*)d_in[5];
    const float* W1 = (const float*)d_in[6];
    const float* b1 = (const float*)d_in[7];
    float* out = (float*)d_out;

    // ws layout (~20.0 MB)
    unsigned short* h0b = (unsigned short*)d_ws;                 // N*64 bf16 = 12.8 MB
    int* scratch = (int*)(h0b + (size_t)NNODES * DD);            // N (sort overflow scratch)
    int* row_ptr = scratch + NNODES;                             // N+1
    unsigned* colpack = (unsigned*)(row_ptr + NNODES + 1);       // E = 6.4 MB
    int* bhist  = (int*)(colpack + NEDGES);                      // 1024
    int* cnt4   = bhist + NBUCK;                                 // 4
    int* bstart = cnt4 + 4;                                      // 1024
    int* gcur   = bstart + NBUCK;                                // 1024
    int* scur   = gcur + NBUCK;                                  // 1
    int* list4  = scur + 1;                                      // 4*512
    float* scal = (float*)(list4 + 4 * CAP4);                    // 2

    (void)hipMemsetAsync(bhist, 0, (NBUCK + 4) * sizeof(int), stream);  // bhist + cnt4

    k_l0h     <<<1536, 256, 0, stream>>>(x, W0, b0, h0b, ei, bhist);
    k_scan1024<<<1, NBUCK, 0, stream>>>(bhist, bstart, gcur, scur, row_ptr);
    k_bin     <<<BIN_BLOCKS, 256, 0, stream>>>(ei, gcur, colpack, cnt4, list4);
    k_sortDH  <<<NBUCK + 1, 256, 0, stream>>>(colpack, bstart, bhist, row_ptr, scratch, scur,
                                              x, W0, b0, cnt4, list4, Wm, bm, W1, b1, scal);
    k_agg     <<<4096, 256, 0, stream>>>(h0b, row_ptr, (const int*)colpack, out);
    k_gemm2   <<<512, 256, 0, stream>>>(out, Wm, bm, W1, b1, scal);
}